// Round 2
// baseline (120.855 us; speedup 1.0000x reference)
//
#include <hip/hip_runtime.h>
#include <math.h>

#define BB 16
#define CC 256
#define HH 64
#define WW 32
#define NN (HH*WW)            // 2048
#define NEGC (-9e15f)

// scratch as module-scope device globals (capture-safe); every buffer is fully
// rewritten each call before any read -> deterministic across replays.
__device__ float g_wlo[BB*CC];            // channel-softmax weight on c-1
__device__ float g_whi[BB*CC];            // channel-softmax weight on c+1
__device__ float g_Wt[CC*64];             // BN-folded transposed weights: Wt[c][k], k<32 alpha, k>=32 sigma
__device__ float g_bias[64];              // BN-folded bias
__device__ float g_as[(size_t)BB*NN*64];  // as[b][p][k]: alpha (0..31), sigma (32..63)
__device__ float g_part[BB*32*256];       // per-(b,tile) partial pair-dots over 64 positions
__device__ float g_w8[(size_t)BB*NN*8];   // spatial softmax weights per position

// ---------------- K1: prep (BN-folded Wt/bias) ----------------
__global__ __launch_bounds__(256) void k_prep(
        const float* __restrict__ wa, const float* __restrict__ ga,
        const float* __restrict__ ba, const float* __restrict__ ma,
        const float* __restrict__ va, const float* __restrict__ wsig,
        const float* __restrict__ gs, const float* __restrict__ bs,
        const float* __restrict__ ms, const float* __restrict__ vs) {
    int t = threadIdx.x;   // t = channel c
    #pragma unroll 4
    for (int k = 0; k < 64; ++k) {
        float inv, w;
        if (k < 32) { inv = ga[k] * rsqrtf(va[k] + 1e-5f); w = wa[k*CC + t]; }
        else { int kk = k - 32; inv = gs[kk] * rsqrtf(vs[kk] + 1e-5f); w = wsig[kk*CC + t]; }
        g_Wt[t*64 + k] = w * inv;
    }
    if (t < 64) {
        float inv, bb, mm;
        if (t < 32) { inv = ga[t] * rsqrtf(va[t] + 1e-5f); bb = ba[t]; mm = ma[t]; }
        else { int kk = t - 32; inv = gs[kk] * rsqrtf(vs[kk] + 1e-5f); bb = bs[kk]; mm = ms[kk]; }
        g_bias[t] = bb - mm * inv;
    }
}

// ---------------- K2: alpha/sigma GEMM + fused adjacent-channel pair dots ----------------
// as[b][p][k] = relu(bias[k] + sum_c Wt[c][k] * x[b][c][p])
// g_part[b][tile][c] = sum over this tile's 64 positions of x[b,c,p]*x[b,c+1,p]
// grid: B*32 blocks; 256 threads = 64 positions x 4 k-groups of 16
__global__ __launch_bounds__(256) void k_gemm(const float* __restrict__ x) {
    __shared__ float lds_g[256];
    int blk = blockIdx.x;
    int b = blk >> 5;
    int tile = blk & 31;
    int t = threadIdx.x;
    int lane = t & 63;
    int p = (tile << 6) + lane;
    int kg = __builtin_amdgcn_readfirstlane(t >> 6);  // wave-uniform k-group
    const float* xp = x + (size_t)b*CC*NN + p;
    const float* wt = g_Wt + kg*16;
    if (t == 255) lds_g[255] = 0.f;   // slot 255 has no pair
    float acc[16];
    #pragma unroll
    for (int i = 0; i < 16; ++i) acc[i] = 0.f;
    float xprev = 0.f;
    #pragma unroll 4
    for (int c = 0; c < CC; ++c) {
        float xv = xp[(size_t)c*NN];
        if (c > 0 && (c & 3) == kg) {          // wave-uniform predicate
            float pp = xv * xprev;             // x[c]*x[c-1] -> pair slot c-1
            #pragma unroll
            for (int off = 1; off < 64; off <<= 1) pp += __shfl_xor(pp, off, 64);
            if (lane == 0) lds_g[c-1] = pp;
        }
        #pragma unroll
        for (int i = 0; i < 16; ++i)
            acc[i] = fmaf(wt[c*64 + i], xv, acc[i]);   // wave-uniform -> s_load
        xprev = xv;
    }
    int kb = kg*16;
    float* o = g_as + (((size_t)b*NN + p) << 6) + kb;
    #pragma unroll
    for (int i = 0; i < 16; ++i)
        o[i] = fmaxf(acc[i] + g_bias[kb + i], 0.f);
    __syncthreads();
    g_part[(b*32 + tile)*256 + t] = lds_g[t];
}

// ---------------- K3: spatial softmax weights (blocks < WBLK) + channel softmax (rest) ----
#define WBLK (BB*NN/32)   // 1024: each block does 32 positions x 8 neighbors
__global__ __launch_bounds__(256) void k_wc() {
    __shared__ float lds_s[256];
    int blk = blockIdx.x;
    int t = threadIdx.x;
    if (blk < WBLK) {
        int pos_local = t >> 3, j = t & 7;
        int idx = blk*32 + pos_local;
        int b = idx >> 11, p = idx & (NN-1);
        int gr = p >> 5, col = p & 31;
        const int dy[8] = {-1,-1,-1, 0,0, 1,1,1};
        const int dx[8] = {-1, 0, 1,-1,1,-1,0,1};
        int qr = gr + dy[j], qc = col + dx[j];
        bool ok = (qr >= 0) && (qr < HH) && (qc >= 0) && (qc < WW);
        int q = ok ? (qr*WW + qc) : p;
        const float4* ap = (const float4*)(g_as + (((size_t)b*NN + p) << 6));
        const float4* sp = (const float4*)(g_as + (((size_t)b*NN + q) << 6) + 32);
        float d = 0.f;
        #pragma unroll
        for (int k4 = 0; k4 < 8; ++k4) {
            float4 a = ap[k4], s = sp[k4];
            d = fmaf(a.x, s.x, d); d = fmaf(a.y, s.y, d);
            d = fmaf(a.z, s.z, d); d = fmaf(a.w, s.w, d);
        }
        float logit = ok ? d : NEGC;
        float m = logit;                       // max over the 8-lane neighbor group
        m = fmaxf(m, __shfl_xor(m, 1, 64));
        m = fmaxf(m, __shfl_xor(m, 2, 64));
        m = fmaxf(m, __shfl_xor(m, 4, 64));
        float e = expf(logit - m);
        float s8 = e;
        s8 += __shfl_xor(s8, 1, 64);
        s8 += __shfl_xor(s8, 2, 64);
        s8 += __shfl_xor(s8, 4, 64);
        g_w8[(size_t)idx*8 + j] = e / s8;
    } else {
        int b = blk - WBLK;
        float s = 0.f;
        #pragma unroll 8
        for (int tile = 0; tile < 32; ++tile) s += g_part[(b*32 + tile)*256 + t];
        lds_s[t] = s;
        __syncthreads();
        int c = t;
        float glo = (c > 0)      ? lds_s[c-1] : NEGC;
        float ghi = (c < CC - 1) ? lds_s[c]   : NEGC;
        float m = fmaxf(glo, ghi);
        float elo = expf(glo - m), ehi = expf(ghi - m);
        float inv = 1.0f / (elo + ehi);
        g_wlo[b*CC + c] = elo * inv;
        g_whi[b*CC + c] = ehi * inv;
    }
}

// ---------------- K4: stencil + channel blend + elu + mix ----------------
// grid: 2048 blocks = b(16) x strip(8 rows)(8) x cgroup(16 ch)(16); 4 waves = 4 ch each
__global__ __launch_bounds__(256) void k_main(const float* __restrict__ x,
                                              const float* __restrict__ gama_p,
                                              float* __restrict__ out) {
    __shared__ float wtab[256][9];   // +1 pad breaks bank conflicts
    int blk = blockIdx.x;
    int b = blk >> 7;
    int strip = (blk >> 4) & 7;
    int cg = blk & 15;
    int t = threadIdx.x;
    int r0 = strip << 3;

    {   // stage this strip's softmax weights into LDS (one thread per position)
        const float4* wsrc = (const float4*)(g_w8 + ((size_t)(b*NN + r0*WW + t))*8);
        float4 w0 = wsrc[0], w1 = wsrc[1];
        wtab[t][0]=w0.x; wtab[t][1]=w0.y; wtab[t][2]=w0.z; wtab[t][3]=w0.w;
        wtab[t][4]=w1.x; wtab[t][5]=w1.y; wtab[t][6]=w1.z; wtab[t][7]=w1.w;
    }
    __syncthreads();

    int wave = __builtin_amdgcn_readfirstlane(t >> 6);
    int lane = t & 63;
    int lrow = lane >> 3;            // row within strip
    int lcq  = (lane & 7) << 2;      // column quad start
    float wq[4][8];                  // channel-invariant weights in registers
    #pragma unroll
    for (int i = 0; i < 4; ++i) {
        int prow = lrow*32 + lcq + i;
        #pragma unroll
        for (int j = 0; j < 8; ++j) wq[i][j] = wtab[prow][j];
    }
    float gama = gama_p[0];
    int c0 = cg*16 + wave*4;
    int pbase = r0*WW + lane*4;      // strip positions are contiguous
    const float* xb = x + (size_t)b*CC*NN;
    float* ob = out + (size_t)b*CC*NN;
    int grow = r0 + lrow;
    int offA = (grow > 0)      ? (pbase - WW) : pbase;  // clamped; masked weights are 0
    int offB = (grow < HH - 1) ? (pbase + WW) : pbase;

    float pm1[4], o0[4];
    {
        int cm1 = (c0 > 0) ? c0 - 1 : 0;              // wlo==0 at c==0
        float4 v = *(const float4*)(xb + (size_t)cm1*NN + pbase);
        pm1[0]=v.x; pm1[1]=v.y; pm1[2]=v.z; pm1[3]=v.w;
        float4 w = *(const float4*)(xb + (size_t)c0*NN + pbase);
        o0[0]=w.x; o0[1]=w.y; o0[2]=w.z; o0[3]=w.w;
    }
    #pragma unroll
    for (int cc = 0; cc < 4; ++cc) {
        int c = c0 + cc;
        int cp1 = (c < CC-1) ? c + 1 : CC-1;          // whi==0 at c==C-1
        float4 v1 = *(const float4*)(xb + (size_t)cp1*NN + pbase);
        float p1[4] = {v1.x, v1.y, v1.z, v1.w};
        float4 va4 = *(const float4*)(xb + (size_t)c*NN + offA);
        float aw[4] = {va4.x, va4.y, va4.z, va4.w};
        float4 vb4 = *(const float4*)(xb + (size_t)c*NN + offB);
        float bw[4] = {vb4.x, vb4.y, vb4.z, vb4.w};
        float al  = __shfl_up(aw[3], 1);
        float ar  = __shfl_down(aw[0], 1);
        float ol  = __shfl_up(o0[3], 1);
        float orr = __shfl_down(o0[0], 1);
        float bl  = __shfl_up(bw[3], 1);
        float br  = __shfl_down(bw[0], 1);
        float wlo_c = g_wlo[b*CC + c];
        float whi_c = g_whi[b*CC + c];
        float res[4];
        #pragma unroll
        for (int i = 0; i < 4; ++i) {
            float ul = (i == 0) ? al  : aw[i-1];
            float uu = aw[i];
            float ur = (i == 3) ? ar  : aw[i+1];
            float ll = (i == 0) ? ol  : o0[i-1];
            float rr = (i == 3) ? orr : o0[i+1];
            float dl = (i == 0) ? bl  : bw[i-1];
            float dd = bw[i];
            float dr = (i == 3) ? br  : bw[i+1];
            float hs = wq[i][0]*ul + wq[i][1]*uu + wq[i][2]*ur
                     + wq[i][3]*ll + wq[i][4]*rr
                     + wq[i][5]*dl + wq[i][6]*dd + wq[i][7]*dr;
            float hp = wlo_c*pm1[i] + whi_c*p1[i];
            float h  = hs + hp;
            float el = (h > 0.f) ? h : expm1f(h);
            res[i] = o0[i] + gama*(el - o0[i]);       // (1-g)x + g*h'
        }
        *(float4*)(ob + (size_t)c*NN + pbase) = make_float4(res[0], res[1], res[2], res[3]);
        #pragma unroll
        for (int i = 0; i < 4; ++i) { pm1[i] = o0[i]; o0[i] = p1[i]; }
    }
}

extern "C" void kernel_launch(void* const* d_in, const int* in_sizes, int n_in,
                              void* d_out, int out_size, void* d_ws, size_t ws_size,
                              hipStream_t stream) {
    const float* x    = (const float*)d_in[0];
    const float* wa   = (const float*)d_in[1];
    const float* ga   = (const float*)d_in[2];
    const float* ba   = (const float*)d_in[3];
    const float* ma   = (const float*)d_in[4];
    const float* va   = (const float*)d_in[5];
    const float* wsig = (const float*)d_in[6];
    const float* gs   = (const float*)d_in[7];
    const float* bs   = (const float*)d_in[8];
    const float* ms   = (const float*)d_in[9];
    const float* vs   = (const float*)d_in[10];
    const float* gama = (const float*)d_in[11];
    float* out = (float*)d_out;

    hipLaunchKernelGGL(k_prep, dim3(1),        dim3(256), 0, stream,
                       wa, ga, ba, ma, va, wsig, gs, bs, ms, vs);
    hipLaunchKernelGGL(k_gemm, dim3(BB*32),    dim3(256), 0, stream, x);
    hipLaunchKernelGGL(k_wc,   dim3(WBLK+BB),  dim3(256), 0, stream);
    hipLaunchKernelGGL(k_main, dim3(2048),     dim3(256), 0, stream, x, gama, out);
}

// Round 3
// 91.993 us; speedup vs baseline: 1.3137x; 1.3137x over previous
//
#include <hip/hip_runtime.h>
#include <math.h>

#define BB 16
#define CC 256
#define HH 64
#define WW 32
#define NN (HH*WW)            // 2048
#define NEGC (-9e15f)

// scratch as module-scope device globals (capture-safe); every buffer is fully
// rewritten each call before any read -> deterministic across replays.
__device__ float g_g[BB*CC];              // adjacent-channel dots, g[b][c] = <x[b,c], x[b,c+1]>
__device__ float g_wlo[BB*CC];            // channel-softmax weight on c-1
__device__ float g_whi[BB*CC];            // channel-softmax weight on c+1
__device__ float g_Wt[CC*64];             // BN-folded transposed weights: Wt[c][k], k<32 alpha, k>=32 sigma
__device__ float g_bias[64];              // BN-folded bias
__device__ float g_as[(size_t)BB*NN*64];  // as[b][p][k]: alpha (0..31), sigma (32..63)
__device__ float g_w8[(size_t)BB*NN*8];   // spatial softmax weights per position

// ---------------- K1: prep (BN-folded Wt/bias) ----------------
__global__ __launch_bounds__(256) void k_prep(
        const float* __restrict__ wa, const float* __restrict__ ga,
        const float* __restrict__ ba, const float* __restrict__ ma,
        const float* __restrict__ va, const float* __restrict__ wsig,
        const float* __restrict__ gs, const float* __restrict__ bs,
        const float* __restrict__ ms, const float* __restrict__ vs) {
    int t = threadIdx.x;   // t = channel c
    #pragma unroll 4
    for (int k = 0; k < 64; ++k) {
        float inv, w;
        if (k < 32) { inv = ga[k] * rsqrtf(va[k] + 1e-5f); w = wa[k*CC + t]; }
        else { int kk = k - 32; inv = gs[kk] * rsqrtf(vs[kk] + 1e-5f); w = wsig[kk*CC + t]; }
        g_Wt[t*64 + k] = w * inv;
    }
    if (t < 64) {
        float inv, bb, mm;
        if (t < 32) { inv = ga[t] * rsqrtf(va[t] + 1e-5f); bb = ba[t]; mm = ma[t]; }
        else { int kk = t - 32; inv = gs[kk] * rsqrtf(vs[kk] + 1e-5f); bb = bs[kk]; mm = ms[kk]; }
        g_bias[t] = bb - mm * inv;
    }
}

// ---------------- K2: adjacent-channel pair dots ----------------
// grid: 512 = b(16) x pairgroup(32).  Group g covers pairs (c,c+1), c = 8g..8g+7.
// Reads rows 8g..8g+8 (9 rows), each thread dots its position-quads across all
// 2048 positions; ONE shuffle-reduce per block at the end.
__global__ __launch_bounds__(256) void k_g(const float* __restrict__ x) {
    __shared__ float red[8][4];
    int blk = blockIdx.x;
    int b = blk >> 5;
    int g8 = blk & 31;
    int c0 = g8 << 3;
    int t = threadIdx.x;
    int lane = t & 63;
    int wave = t >> 6;
    const float* xb = x + ((size_t)b*CC + c0)*NN;
    float pp[8];
    #pragma unroll
    for (int r = 0; r < 8; ++r) pp[r] = 0.f;
    bool has9 = (c0 + 8) < CC;
    #pragma unroll
    for (int half = 0; half < 2; ++half) {
        int p = t*4 + half*1024;
        float4 v[9];
        #pragma unroll
        for (int r = 0; r < 9; ++r)
            v[r] = (r < 8 || has9) ? *(const float4*)(xb + (size_t)r*NN + p)
                                   : make_float4(0.f,0.f,0.f,0.f);
        #pragma unroll
        for (int r = 0; r < 8; ++r) {
            pp[r] = fmaf(v[r].x, v[r+1].x, pp[r]);
            pp[r] = fmaf(v[r].y, v[r+1].y, pp[r]);
            pp[r] = fmaf(v[r].z, v[r+1].z, pp[r]);
            pp[r] = fmaf(v[r].w, v[r+1].w, pp[r]);
        }
    }
    #pragma unroll
    for (int r = 0; r < 8; ++r) {
        #pragma unroll
        for (int off = 1; off < 64; off <<= 1) pp[r] += __shfl_xor(pp[r], off, 64);
    }
    if (lane == 0) {
        #pragma unroll
        for (int r = 0; r < 8; ++r) red[r][wave] = pp[r];
    }
    __syncthreads();
    if (t < 8) {
        int c = c0 + t;
        if (c < CC - 1)
            g_g[b*CC + c] = red[t][0] + red[t][1] + red[t][2] + red[t][3];
    }
}

// ---------------- K3: alpha/sigma GEMM, register-tiled ----------------
// as[b][p][k] = relu(bias[k] + sum_c Wt[c][k] * x[b][c][p])
// grid: 512 = b(16) x ptile(32, 64 positions).  thread: kg=t&15 (4 k's), q=t>>4 (4 pos).
__global__ __launch_bounds__(256) void k_gemm(const float* __restrict__ x) {
    int blk = blockIdx.x;
    int b = blk >> 5;
    int tile = blk & 31;
    int t = threadIdx.x;
    int kg = t & 15;
    int q  = t >> 4;
    int p0 = tile*64 + q*4;
    const float* xp = x + (size_t)b*CC*NN + p0;
    const float* wp = g_Wt + kg*4;
    float4 bias = *(const float4*)(g_bias + kg*4);
    float acc[4][4];
    #pragma unroll
    for (int i = 0; i < 4; ++i)
        #pragma unroll
        for (int j = 0; j < 4; ++j) acc[i][j] = 0.f;
    #pragma unroll 4
    for (int c = 0; c < CC; ++c) {
        float4 xv = *(const float4*)(xp + (size_t)c*NN);
        float4 wv = *(const float4*)(wp + c*64);
        acc[0][0] = fmaf(xv.x, wv.x, acc[0][0]);
        acc[0][1] = fmaf(xv.x, wv.y, acc[0][1]);
        acc[0][2] = fmaf(xv.x, wv.z, acc[0][2]);
        acc[0][3] = fmaf(xv.x, wv.w, acc[0][3]);
        acc[1][0] = fmaf(xv.y, wv.x, acc[1][0]);
        acc[1][1] = fmaf(xv.y, wv.y, acc[1][1]);
        acc[1][2] = fmaf(xv.y, wv.z, acc[1][2]);
        acc[1][3] = fmaf(xv.y, wv.w, acc[1][3]);
        acc[2][0] = fmaf(xv.z, wv.x, acc[2][0]);
        acc[2][1] = fmaf(xv.z, wv.y, acc[2][1]);
        acc[2][2] = fmaf(xv.z, wv.z, acc[2][2]);
        acc[2][3] = fmaf(xv.z, wv.w, acc[2][3]);
        acc[3][0] = fmaf(xv.w, wv.x, acc[3][0]);
        acc[3][1] = fmaf(xv.w, wv.y, acc[3][1]);
        acc[3][2] = fmaf(xv.w, wv.z, acc[3][2]);
        acc[3][3] = fmaf(xv.w, wv.w, acc[3][3]);
    }
    float* o = g_as + (((size_t)b*NN + p0) << 6) + kg*4;
    #pragma unroll
    for (int pi = 0; pi < 4; ++pi) {
        float4 r;
        r.x = fmaxf(acc[pi][0] + bias.x, 0.f);
        r.y = fmaxf(acc[pi][1] + bias.y, 0.f);
        r.z = fmaxf(acc[pi][2] + bias.z, 0.f);
        r.w = fmaxf(acc[pi][3] + bias.w, 0.f);
        *(float4*)(o + (pi << 6)) = r;
    }
}

// ---------------- K4: spatial softmax weights (blocks < WBLK) + channel softmax (rest) ----
#define WBLK (BB*NN/32)   // 1024: each block does 32 positions x 8 neighbors
__global__ __launch_bounds__(256) void k_wc() {
    int blk = blockIdx.x;
    int t = threadIdx.x;
    if (blk < WBLK) {
        int pos_local = t >> 3, j = t & 7;
        int idx = blk*32 + pos_local;
        int b = idx >> 11, p = idx & (NN-1);
        int gr = p >> 5, col = p & 31;
        const int dy[8] = {-1,-1,-1, 0,0, 1,1,1};
        const int dx[8] = {-1, 0, 1,-1,1,-1,0,1};
        int qr = gr + dy[j], qc = col + dx[j];
        bool ok = (qr >= 0) && (qr < HH) && (qc >= 0) && (qc < WW);
        int q = ok ? (qr*WW + qc) : p;
        const float4* ap = (const float4*)(g_as + (((size_t)b*NN + p) << 6));
        const float4* sp = (const float4*)(g_as + (((size_t)b*NN + q) << 6) + 32);
        float d = 0.f;
        #pragma unroll
        for (int k4 = 0; k4 < 8; ++k4) {
            float4 a = ap[k4], s = sp[k4];
            d = fmaf(a.x, s.x, d); d = fmaf(a.y, s.y, d);
            d = fmaf(a.z, s.z, d); d = fmaf(a.w, s.w, d);
        }
        float logit = ok ? d : NEGC;
        float m = logit;                       // max over the 8-lane neighbor group
        m = fmaxf(m, __shfl_xor(m, 1, 64));
        m = fmaxf(m, __shfl_xor(m, 2, 64));
        m = fmaxf(m, __shfl_xor(m, 4, 64));
        float e = expf(logit - m);
        float s8 = e;
        s8 += __shfl_xor(s8, 1, 64);
        s8 += __shfl_xor(s8, 2, 64);
        s8 += __shfl_xor(s8, 4, 64);
        g_w8[(size_t)idx*8 + j] = e / s8;
    } else {
        int b = blk - WBLK;
        int c = t;
        float glo = (c > 0)      ? g_g[b*CC + c - 1] : NEGC;
        float ghi = (c < CC - 1) ? g_g[b*CC + c]     : NEGC;
        float m = fmaxf(glo, ghi);
        float elo = expf(glo - m), ehi = expf(ghi - m);
        float inv = 1.0f / (elo + ehi);
        g_wlo[b*CC + c] = elo * inv;
        g_whi[b*CC + c] = ehi * inv;
    }
}

// ---------------- K5: stencil + channel blend + elu + mix ----------------
// grid: 2048 blocks = b(16) x strip(8 rows)(8) x cgroup(16 ch)(16); 4 waves = 4 ch each
__global__ __launch_bounds__(256) void k_main(const float* __restrict__ x,
                                              const float* __restrict__ gama_p,
                                              float* __restrict__ out) {
    __shared__ float wtab[256][9];   // +1 pad breaks bank conflicts
    int blk = blockIdx.x;
    int b = blk >> 7;
    int strip = (blk >> 4) & 7;
    int cg = blk & 15;
    int t = threadIdx.x;
    int r0 = strip << 3;

    {   // stage this strip's softmax weights into LDS (one thread per position)
        const float4* wsrc = (const float4*)(g_w8 + ((size_t)(b*NN + r0*WW + t))*8);
        float4 w0 = wsrc[0], w1 = wsrc[1];
        wtab[t][0]=w0.x; wtab[t][1]=w0.y; wtab[t][2]=w0.z; wtab[t][3]=w0.w;
        wtab[t][4]=w1.x; wtab[t][5]=w1.y; wtab[t][6]=w1.z; wtab[t][7]=w1.w;
    }
    __syncthreads();

    int wave = __builtin_amdgcn_readfirstlane(t >> 6);
    int lane = t & 63;
    int lrow = lane >> 3;            // row within strip
    int lcq  = (lane & 7) << 2;      // column quad start
    float wq[4][8];                  // channel-invariant weights in registers
    #pragma unroll
    for (int i = 0; i < 4; ++i) {
        int prow = lrow*32 + lcq + i;
        #pragma unroll
        for (int j = 0; j < 8; ++j) wq[i][j] = wtab[prow][j];
    }
    float gama = gama_p[0];
    int c0 = cg*16 + wave*4;
    int pbase = r0*WW + lane*4;      // strip positions are contiguous
    const float* xb = x + (size_t)b*CC*NN;
    float* ob = out + (size_t)b*CC*NN;
    int grow = r0 + lrow;
    int offA = (grow > 0)      ? (pbase - WW) : pbase;  // clamped; masked weights are 0
    int offB = (grow < HH - 1) ? (pbase + WW) : pbase;

    float pm1[4], o0[4];
    {
        int cm1 = (c0 > 0) ? c0 - 1 : 0;              // wlo==0 at c==0
        float4 v = *(const float4*)(xb + (size_t)cm1*NN + pbase);
        pm1[0]=v.x; pm1[1]=v.y; pm1[2]=v.z; pm1[3]=v.w;
        float4 w = *(const float4*)(xb + (size_t)c0*NN + pbase);
        o0[0]=w.x; o0[1]=w.y; o0[2]=w.z; o0[3]=w.w;
    }
    #pragma unroll
    for (int cc = 0; cc < 4; ++cc) {
        int c = c0 + cc;
        int cp1 = (c < CC-1) ? c + 1 : CC-1;          // whi==0 at c==C-1
        float4 v1 = *(const float4*)(xb + (size_t)cp1*NN + pbase);
        float p1[4] = {v1.x, v1.y, v1.z, v1.w};
        float4 va4 = *(const float4*)(xb + (size_t)c*NN + offA);
        float aw[4] = {va4.x, va4.y, va4.z, va4.w};
        float4 vb4 = *(const float4*)(xb + (size_t)c*NN + offB);
        float bw[4] = {vb4.x, vb4.y, vb4.z, vb4.w};
        float al  = __shfl_up(aw[3], 1);
        float ar  = __shfl_down(aw[0], 1);
        float ol  = __shfl_up(o0[3], 1);
        float orr = __shfl_down(o0[0], 1);
        float bl  = __shfl_up(bw[3], 1);
        float br  = __shfl_down(bw[0], 1);
        float wlo_c = g_wlo[b*CC + c];
        float whi_c = g_whi[b*CC + c];
        float res[4];
        #pragma unroll
        for (int i = 0; i < 4; ++i) {
            float ul = (i == 0) ? al  : aw[i-1];
            float uu = aw[i];
            float ur = (i == 3) ? ar  : aw[i+1];
            float ll = (i == 0) ? ol  : o0[i-1];
            float rr = (i == 3) ? orr : o0[i+1];
            float dl = (i == 0) ? bl  : bw[i-1];
            float dd = bw[i];
            float dr = (i == 3) ? br  : bw[i+1];
            float hs = wq[i][0]*ul + wq[i][1]*uu + wq[i][2]*ur
                     + wq[i][3]*ll + wq[i][4]*rr
                     + wq[i][5]*dl + wq[i][6]*dd + wq[i][7]*dr;
            float hp = wlo_c*pm1[i] + whi_c*p1[i];
            float h  = hs + hp;
            float el = (h > 0.f) ? h : expm1f(h);
            res[i] = o0[i] + gama*(el - o0[i]);       // (1-g)x + g*h'
        }
        *(float4*)(ob + (size_t)c*NN + pbase) = make_float4(res[0], res[1], res[2], res[3]);
        #pragma unroll
        for (int i = 0; i < 4; ++i) { pm1[i] = o0[i]; o0[i] = p1[i]; }
    }
}

extern "C" void kernel_launch(void* const* d_in, const int* in_sizes, int n_in,
                              void* d_out, int out_size, void* d_ws, size_t ws_size,
                              hipStream_t stream) {
    const float* x    = (const float*)d_in[0];
    const float* wa   = (const float*)d_in[1];
    const float* ga   = (const float*)d_in[2];
    const float* ba   = (const float*)d_in[3];
    const float* ma   = (const float*)d_in[4];
    const float* va   = (const float*)d_in[5];
    const float* wsig = (const float*)d_in[6];
    const float* gs   = (const float*)d_in[7];
    const float* bs   = (const float*)d_in[8];
    const float* ms   = (const float*)d_in[9];
    const float* vs   = (const float*)d_in[10];
    const float* gama = (const float*)d_in[11];
    float* out = (float*)d_out;

    hipLaunchKernelGGL(k_prep, dim3(1),        dim3(256), 0, stream,
                       wa, ga, ba, ma, va, wsig, gs, bs, ms, vs);
    hipLaunchKernelGGL(k_g,    dim3(512),      dim3(256), 0, stream, x);
    hipLaunchKernelGGL(k_gemm, dim3(512),      dim3(256), 0, stream, x);
    hipLaunchKernelGGL(k_wc,   dim3(WBLK+BB),  dim3(256), 0, stream);
    hipLaunchKernelGGL(k_main, dim3(2048),     dim3(256), 0, stream, x, gama, out);
}

// Round 4
// 82.101 us; speedup vs baseline: 1.4720x; 1.1205x over previous
//
#include <hip/hip_runtime.h>
#include <math.h>

#define BB 16
#define CC 256
#define HH 64
#define WW 32
#define NN (HH*WW)            // 2048
#define NEGC (-9e15f)

// scratch as module-scope device globals (capture-safe); every buffer is fully
// rewritten each call before any read -> deterministic across replays.
__device__ float g_g[BB*CC];              // adjacent-channel dots, g[b][c] = <x[b,c], x[b,c+1]>
__device__ float g_wlo[BB*CC];            // channel-softmax weight on c-1
__device__ float g_whi[BB*CC];            // channel-softmax weight on c+1
__device__ float g_Wt[CC*64];             // BN-folded transposed weights: Wt[c][k], k<32 alpha, k>=32 sigma
__device__ float g_bias[64];              // BN-folded bias
__device__ float g_as[(size_t)BB*NN*64];  // as[b][p][k]: alpha (0..31), sigma (32..63)
__device__ float g_w8[(size_t)BB*NN*8];   // spatial softmax weights per position

// ---------------- K1: adjacent-channel pair dots  (+ prep folded in at blk==512) ----
// grid: 513.  blk<512: b(16) x pairgroup(32); group covers pairs c=8g..8g+7,
// reads rows 8g..8g+8, one shuffle-reduce per block at the end.
__global__ __launch_bounds__(256) void k_g(const float* __restrict__ x,
        const float* __restrict__ wa, const float* __restrict__ ga,
        const float* __restrict__ ba, const float* __restrict__ ma,
        const float* __restrict__ va, const float* __restrict__ wsig,
        const float* __restrict__ gs, const float* __restrict__ bs,
        const float* __restrict__ ms, const float* __restrict__ vs) {
    int blk = blockIdx.x;
    int t = threadIdx.x;
    if (blk == 512) {                      // prep: BN-folded Wt/bias
        #pragma unroll 4
        for (int k = 0; k < 64; ++k) {
            float inv, w;
            if (k < 32) { inv = ga[k] * rsqrtf(va[k] + 1e-5f); w = wa[k*CC + t]; }
            else { int kk = k - 32; inv = gs[kk] * rsqrtf(vs[kk] + 1e-5f); w = wsig[kk*CC + t]; }
            g_Wt[t*64 + k] = w * inv;
        }
        if (t < 64) {
            float inv, bb, mm;
            if (t < 32) { inv = ga[t] * rsqrtf(va[t] + 1e-5f); bb = ba[t]; mm = ma[t]; }
            else { int kk = t - 32; inv = gs[kk] * rsqrtf(vs[kk] + 1e-5f); bb = bs[kk]; mm = ms[kk]; }
            g_bias[t] = bb - mm * inv;
        }
        return;
    }
    __shared__ float red[8][4];
    int b = blk >> 5;
    int g8 = blk & 31;
    int c0 = g8 << 3;
    int lane = t & 63;
    int wave = t >> 6;
    const float* xb = x + ((size_t)b*CC + c0)*NN;
    float pp[8];
    #pragma unroll
    for (int r = 0; r < 8; ++r) pp[r] = 0.f;
    bool has9 = (c0 + 8) < CC;
    #pragma unroll
    for (int half = 0; half < 2; ++half) {
        int p = t*4 + half*1024;
        float4 v[9];
        #pragma unroll
        for (int r = 0; r < 9; ++r)
            v[r] = (r < 8 || has9) ? *(const float4*)(xb + (size_t)r*NN + p)
                                   : make_float4(0.f,0.f,0.f,0.f);
        #pragma unroll
        for (int r = 0; r < 8; ++r) {
            pp[r] = fmaf(v[r].x, v[r+1].x, pp[r]);
            pp[r] = fmaf(v[r].y, v[r+1].y, pp[r]);
            pp[r] = fmaf(v[r].z, v[r+1].z, pp[r]);
            pp[r] = fmaf(v[r].w, v[r+1].w, pp[r]);
        }
    }
    #pragma unroll
    for (int r = 0; r < 8; ++r) {
        #pragma unroll
        for (int off = 1; off < 64; off <<= 1) pp[r] += __shfl_xor(pp[r], off, 64);
    }
    if (lane == 0) {
        #pragma unroll
        for (int r = 0; r < 8; ++r) red[r][wave] = pp[r];
    }
    __syncthreads();
    if (t < 8) {
        int c = c0 + t;
        if (c < CC - 1)
            g_g[b*CC + c] = red[t][0] + red[t][1] + red[t][2] + red[t][3];
    }
}

// ---------------- K2: alpha/sigma GEMM, LDS-staged x tile ----------------
// as[b][p][k] = relu(bias[k] + sum_c Wt[c][k] * x[b][c][p])
// grid: 512 = b(16) x ptile(32, 64 positions).  Stage x[256c][64pos] (64 KB) once,
// then compute from LDS.  thread: kg=t&15 (4 k's), q=t>>4 (4 pos).
__global__ __launch_bounds__(256) void k_gemm(const float* __restrict__ x) {
    __shared__ float x_lds[CC][64];
    int blk = blockIdx.x;
    int b = blk >> 5;
    int tile = blk & 31;
    int t = threadIdx.x;
    const float* xb = x + (size_t)b*CC*NN + tile*64;
    // stage: 16 coalesced dwordx4 per thread, issued back-to-back
    #pragma unroll
    for (int i = 0; i < 16; ++i) {
        int idx = t + i*256;           // quad index in tile
        int c = idx >> 4;
        int quad = idx & 15;
        float4 v = *(const float4*)(xb + (size_t)c*NN + quad*4);
        *(float4*)(&x_lds[c][quad*4]) = v;
    }
    __syncthreads();

    int kg = t & 15;
    int q  = t >> 4;
    const float* wp = g_Wt + kg*4;
    float4 bias = *(const float4*)(g_bias + kg*4);
    float acc[4][4];
    #pragma unroll
    for (int i = 0; i < 4; ++i)
        #pragma unroll
        for (int j = 0; j < 4; ++j) acc[i][j] = 0.f;
    #pragma unroll 8
    for (int c = 0; c < CC; ++c) {
        float4 xv = *(const float4*)(&x_lds[c][q*4]);   // LDS broadcast across kg lanes
        float4 wv = *(const float4*)(wp + c*64);         // L1-resident, broadcast across q lanes
        acc[0][0] = fmaf(xv.x, wv.x, acc[0][0]);
        acc[0][1] = fmaf(xv.x, wv.y, acc[0][1]);
        acc[0][2] = fmaf(xv.x, wv.z, acc[0][2]);
        acc[0][3] = fmaf(xv.x, wv.w, acc[0][3]);
        acc[1][0] = fmaf(xv.y, wv.x, acc[1][0]);
        acc[1][1] = fmaf(xv.y, wv.y, acc[1][1]);
        acc[1][2] = fmaf(xv.y, wv.z, acc[1][2]);
        acc[1][3] = fmaf(xv.y, wv.w, acc[1][3]);
        acc[2][0] = fmaf(xv.z, wv.x, acc[2][0]);
        acc[2][1] = fmaf(xv.z, wv.y, acc[2][1]);
        acc[2][2] = fmaf(xv.z, wv.z, acc[2][2]);
        acc[2][3] = fmaf(xv.z, wv.w, acc[2][3]);
        acc[3][0] = fmaf(xv.w, wv.x, acc[3][0]);
        acc[3][1] = fmaf(xv.w, wv.y, acc[3][1]);
        acc[3][2] = fmaf(xv.w, wv.z, acc[3][2]);
        acc[3][3] = fmaf(xv.w, wv.w, acc[3][3]);
    }
    int p0 = tile*64 + q*4;
    float* o = g_as + (((size_t)b*NN + p0) << 6) + kg*4;
    #pragma unroll
    for (int pi = 0; pi < 4; ++pi) {
        float4 r;
        r.x = fmaxf(acc[pi][0] + bias.x, 0.f);
        r.y = fmaxf(acc[pi][1] + bias.y, 0.f);
        r.z = fmaxf(acc[pi][2] + bias.z, 0.f);
        r.w = fmaxf(acc[pi][3] + bias.w, 0.f);
        *(float4*)(o + (pi << 6)) = r;
    }
}

// ---------------- K3: spatial softmax weights (blocks < WBLK) + channel softmax (rest) ----
#define WBLK (BB*NN/32)   // 1024: each block does 32 positions x 8 neighbors
__global__ __launch_bounds__(256) void k_wc() {
    int blk = blockIdx.x;
    int t = threadIdx.x;
    if (blk < WBLK) {
        int pos_local = t >> 3, j = t & 7;
        int idx = blk*32 + pos_local;
        int b = idx >> 11, p = idx & (NN-1);
        int gr = p >> 5, col = p & 31;
        const int dy[8] = {-1,-1,-1, 0,0, 1,1,1};
        const int dx[8] = {-1, 0, 1,-1,1,-1,0,1};
        int qr = gr + dy[j], qc = col + dx[j];
        bool ok = (qr >= 0) && (qr < HH) && (qc >= 0) && (qc < WW);
        int q = ok ? (qr*WW + qc) : p;
        const float4* ap = (const float4*)(g_as + (((size_t)b*NN + p) << 6));
        const float4* sp = (const float4*)(g_as + (((size_t)b*NN + q) << 6) + 32);
        float d = 0.f;
        #pragma unroll
        for (int k4 = 0; k4 < 8; ++k4) {
            float4 a = ap[k4], s = sp[k4];
            d = fmaf(a.x, s.x, d); d = fmaf(a.y, s.y, d);
            d = fmaf(a.z, s.z, d); d = fmaf(a.w, s.w, d);
        }
        float logit = ok ? d : NEGC;
        float m = logit;                       // max over the 8-lane neighbor group
        m = fmaxf(m, __shfl_xor(m, 1, 64));
        m = fmaxf(m, __shfl_xor(m, 2, 64));
        m = fmaxf(m, __shfl_xor(m, 4, 64));
        float e = expf(logit - m);
        float s8 = e;
        s8 += __shfl_xor(s8, 1, 64);
        s8 += __shfl_xor(s8, 2, 64);
        s8 += __shfl_xor(s8, 4, 64);
        g_w8[(size_t)idx*8 + j] = e / s8;
    } else {
        int b = blk - WBLK;
        int c = t;
        float glo = (c > 0)      ? g_g[b*CC + c - 1] : NEGC;
        float ghi = (c < CC - 1) ? g_g[b*CC + c]     : NEGC;
        float m = fmaxf(glo, ghi);
        float elo = expf(glo - m), ehi = expf(ghi - m);
        float inv = 1.0f / (elo + ehi);
        g_wlo[b*CC + c] = elo * inv;
        g_whi[b*CC + c] = ehi * inv;
    }
}

// ---------------- K4: stencil + channel blend + elu + mix (LDS-staged halo tile) ----
// grid: 2048 blocks = b(16) x strip(8 rows)(8) x cgroup(16 ch)(16); 4 waves = 4 ch each
// x tile staged in LDS: 18 ch slots (c0-1..c0+16) x 10 row slots (r0-1..r0+8) x 32 cols,
// clamped at stage time (replicates per-thread clamping of the unstaged version).
// Row stride 36 floats => 8 wave-rows hit disjoint 4-bank groups (no conflicts).
__global__ __launch_bounds__(256) void k_main(const float* __restrict__ x,
                                              const float* __restrict__ gama_p,
                                              float* __restrict__ out) {
    __shared__ float wtab[256][9];
    __shared__ float xt[18*10*36];
    int blk = blockIdx.x;
    int b = blk >> 7;
    int strip = (blk >> 4) & 7;
    int cg = blk & 15;
    int t = threadIdx.x;
    int r0 = strip << 3;
    int c0 = cg << 4;
    const float* xb = x + (size_t)b*CC*NN;

    {   // stage softmax weights (one thread per position)
        const float4* wsrc = (const float4*)(g_w8 + ((size_t)(b*NN + r0*WW + t))*8);
        float4 w0 = wsrc[0], w1 = wsrc[1];
        wtab[t][0]=w0.x; wtab[t][1]=w0.y; wtab[t][2]=w0.z; wtab[t][3]=w0.w;
        wtab[t][4]=w1.x; wtab[t][5]=w1.y; wtab[t][6]=w1.z; wtab[t][7]=w1.w;
    }
    // stage x halo tile: 18*10 = 180 row-segments x 8 quads = 1440 float4
    for (int i = t; i < 1440; i += 256) {
        int seg = i >> 3, quad = i & 7;
        int ch_s = seg / 10, r_s = seg - ch_s*10;
        int gc = c0 - 1 + ch_s;  gc = (gc < 0) ? 0 : (gc > CC-1 ? CC-1 : gc);
        int gr = r0 - 1 + r_s;   gr = (gr < 0) ? 0 : (gr > HH-1 ? HH-1 : gr);
        float4 v = *(const float4*)(xb + (size_t)gc*NN + gr*WW + quad*4);
        *(float4*)(&xt[(ch_s*10 + r_s)*36 + quad*4]) = v;
    }
    __syncthreads();

    int wave = __builtin_amdgcn_readfirstlane(t >> 6);
    int lane = t & 63;
    int lrow = lane >> 3;            // row within strip
    int lcq  = (lane & 7) << 2;      // column quad start
    float wq[4][8];
    #pragma unroll
    for (int i = 0; i < 4; ++i) {
        int prow = lrow*32 + lcq + i;
        #pragma unroll
        for (int j = 0; j < 8; ++j) wq[i][j] = wtab[prow][j];
    }
    float gama = gama_p[0];
    int cw0 = wave*4;                // this wave's first channel (slot cw0+1)
    int pbase = r0*WW + lane*4;      // for the global store
    float* ob = out + (size_t)b*CC*NN;

    // LDS base for this thread's column quad; channel slot s, row slot r:
    //   xt[(s*10 + r)*36 + lcq]
    float pm1[4], o0[4];
    {
        float4 v = *(const float4*)(&xt[((cw0+0)*10 + (lrow+1))*36 + lcq]);   // slot c0-1+cw0
        pm1[0]=v.x; pm1[1]=v.y; pm1[2]=v.z; pm1[3]=v.w;
        float4 w = *(const float4*)(&xt[((cw0+1)*10 + (lrow+1))*36 + lcq]);   // own channel
        o0[0]=w.x; o0[1]=w.y; o0[2]=w.z; o0[3]=w.w;
    }
    #pragma unroll
    for (int cc = 0; cc < 4; ++cc) {
        int c = c0 + cw0 + cc;
        int slot = cw0 + 1 + cc;
        float4 v1 = *(const float4*)(&xt[((slot+1)*10 + (lrow+1))*36 + lcq]); // c+1 (clamped)
        float p1[4] = {v1.x, v1.y, v1.z, v1.w};
        float4 va4 = *(const float4*)(&xt[(slot*10 + lrow    )*36 + lcq]);    // row above (clamped)
        float aw[4] = {va4.x, va4.y, va4.z, va4.w};
        float4 vb4 = *(const float4*)(&xt[(slot*10 + lrow + 2)*36 + lcq]);    // row below (clamped)
        float bw[4] = {vb4.x, vb4.y, vb4.z, vb4.w};
        float al  = __shfl_up(aw[3], 1);
        float ar  = __shfl_down(aw[0], 1);
        float ol  = __shfl_up(o0[3], 1);
        float orr = __shfl_down(o0[0], 1);
        float bl  = __shfl_up(bw[3], 1);
        float br  = __shfl_down(bw[0], 1);
        float wlo_c = g_wlo[b*CC + c];
        float whi_c = g_whi[b*CC + c];
        float res[4];
        #pragma unroll
        for (int i = 0; i < 4; ++i) {
            float ul = (i == 0) ? al  : aw[i-1];
            float uu = aw[i];
            float ur = (i == 3) ? ar  : aw[i+1];
            float ll = (i == 0) ? ol  : o0[i-1];
            float rr = (i == 3) ? orr : o0[i+1];
            float dl = (i == 0) ? bl  : bw[i-1];
            float dd = bw[i];
            float dr = (i == 3) ? br  : bw[i+1];
            float hs = wq[i][0]*ul + wq[i][1]*uu + wq[i][2]*ur
                     + wq[i][3]*ll + wq[i][4]*rr
                     + wq[i][5]*dl + wq[i][6]*dd + wq[i][7]*dr;
            float hp = wlo_c*pm1[i] + whi_c*p1[i];
            float h  = hs + hp;
            float el = (h > 0.f) ? h : expm1f(h);
            res[i] = o0[i] + gama*(el - o0[i]);       // (1-g)x + g*h'
        }
        *(float4*)(ob + (size_t)c*NN + pbase) = make_float4(res[0], res[1], res[2], res[3]);
        #pragma unroll
        for (int i = 0; i < 4; ++i) { pm1[i] = o0[i]; o0[i] = p1[i]; }
    }
}

extern "C" void kernel_launch(void* const* d_in, const int* in_sizes, int n_in,
                              void* d_out, int out_size, void* d_ws, size_t ws_size,
                              hipStream_t stream) {
    const float* x    = (const float*)d_in[0];
    const float* wa   = (const float*)d_in[1];
    const float* ga   = (const float*)d_in[2];
    const float* ba   = (const float*)d_in[3];
    const float* ma   = (const float*)d_in[4];
    const float* va   = (const float*)d_in[5];
    const float* wsig = (const float*)d_in[6];
    const float* gs   = (const float*)d_in[7];
    const float* bs   = (const float*)d_in[8];
    const float* ms   = (const float*)d_in[9];
    const float* vs   = (const float*)d_in[10];
    const float* gama = (const float*)d_in[11];
    float* out = (float*)d_out;

    hipLaunchKernelGGL(k_g,    dim3(513),      dim3(256), 0, stream, x,
                       wa, ga, ba, ma, va, wsig, gs, bs, ms, vs);
    hipLaunchKernelGGL(k_gemm, dim3(512),      dim3(256), 0, stream, x);
    hipLaunchKernelGGL(k_wc,   dim3(WBLK+BB),  dim3(256), 0, stream);
    hipLaunchKernelGGL(k_main, dim3(2048),     dim3(256), 0, stream, x, gama, out);
}

// Round 5
// 80.507 us; speedup vs baseline: 1.5012x; 1.0198x over previous
//
#include <hip/hip_runtime.h>
#include <math.h>

#define BB 16
#define CC 256
#define HH 64
#define WW 32
#define NN (HH*WW)            // 2048
#define NEGC (-9e15f)

// scratch as module-scope device globals (capture-safe); every buffer is fully
// rewritten each call before any read -> deterministic across replays.
__device__ float g_wlo[BB*CC];            // channel-softmax weight on c-1
__device__ float g_whi[BB*CC];            // channel-softmax weight on c+1
__device__ float g_Wt[CC*64];             // BN-folded transposed weights: Wt[c][k], k<32 alpha, k>=32 sigma
__device__ float g_bias[64];              // BN-folded bias
__device__ float g_as[(size_t)BB*NN*64];  // as[b][p][k]: alpha (0..31), sigma (32..63)
__device__ float g_part[BB*32*256];       // per-(b,tile) pair-dot partials over 64 positions
__device__ float g_w8[(size_t)BB*NN*8];   // spatial softmax weights per position

// ---------------- K1: prep (BN-folded Wt/bias) ----------------
__global__ __launch_bounds__(256) void k_prep(
        const float* __restrict__ wa, const float* __restrict__ ga,
        const float* __restrict__ ba, const float* __restrict__ ma,
        const float* __restrict__ va, const float* __restrict__ wsig,
        const float* __restrict__ gs, const float* __restrict__ bs,
        const float* __restrict__ ms, const float* __restrict__ vs) {
    int t = threadIdx.x;   // t = channel c
    #pragma unroll 4
    for (int k = 0; k < 64; ++k) {
        float inv, w;
        if (k < 32) { inv = ga[k] * rsqrtf(va[k] + 1e-5f); w = wa[k*CC + t]; }
        else { int kk = k - 32; inv = gs[kk] * rsqrtf(vs[kk] + 1e-5f); w = wsig[kk*CC + t]; }
        g_Wt[t*64 + k] = w * inv;
    }
    if (t < 64) {
        float inv, bb, mm;
        if (t < 32) { inv = ga[t] * rsqrtf(va[t] + 1e-5f); bb = ba[t]; mm = ma[t]; }
        else { int kk = t - 32; inv = gs[kk] * rsqrtf(vs[kk] + 1e-5f); bb = bs[kk]; mm = ms[kk]; }
        g_bias[t] = bb - mm * inv;
    }
}

// ---------------- K2: alpha/sigma GEMM + pair dots, LDS-staged x tile ----------------
// as[b][p][k] = relu(bias[k] + sum_c Wt[c][k] * x[b][c][p])
// g_part[b][tile][c] = sum over the tile's 64 positions of x[b,c,p]*x[b,c+1,p]
// grid: 512 = b(16) x ptile(32, 64 positions).  Stage x[256c][64pos] (64 KB) once.
__global__ __launch_bounds__(256) void k_gemm(const float* __restrict__ x) {
    __shared__ float x_lds[CC][64];
    int blk = blockIdx.x;
    int b = blk >> 5;
    int tile = blk & 31;
    int t = threadIdx.x;
    const float* xb = x + (size_t)b*CC*NN + tile*64;
    // stage: 16 coalesced dwordx4 per thread, issued back-to-back
    #pragma unroll
    for (int i = 0; i < 16; ++i) {
        int idx = t + i*256;           // quad index in tile
        int c = idx >> 4;
        int quad = idx & 15;
        float4 v = *(const float4*)(xb + (size_t)c*NN + quad*4);
        *(float4*)(&x_lds[c][quad*4]) = v;
    }
    __syncthreads();

    int kg = t & 15;
    int q  = t >> 4;
    const float* wp = g_Wt + kg*4;
    float4 bias = *(const float4*)(g_bias + kg*4);
    float acc[4][4];
    #pragma unroll
    for (int i = 0; i < 4; ++i)
        #pragma unroll
        for (int j = 0; j < 4; ++j) acc[i][j] = 0.f;
    #pragma unroll 8
    for (int c = 0; c < CC; ++c) {
        float4 xv = *(const float4*)(&x_lds[c][q*4]);   // LDS broadcast across kg lanes
        float4 wv = *(const float4*)(wp + c*64);         // L1/L2-resident
        acc[0][0] = fmaf(xv.x, wv.x, acc[0][0]);
        acc[0][1] = fmaf(xv.x, wv.y, acc[0][1]);
        acc[0][2] = fmaf(xv.x, wv.z, acc[0][2]);
        acc[0][3] = fmaf(xv.x, wv.w, acc[0][3]);
        acc[1][0] = fmaf(xv.y, wv.x, acc[1][0]);
        acc[1][1] = fmaf(xv.y, wv.y, acc[1][1]);
        acc[1][2] = fmaf(xv.y, wv.z, acc[1][2]);
        acc[1][3] = fmaf(xv.y, wv.w, acc[1][3]);
        acc[2][0] = fmaf(xv.z, wv.x, acc[2][0]);
        acc[2][1] = fmaf(xv.z, wv.y, acc[2][1]);
        acc[2][2] = fmaf(xv.z, wv.z, acc[2][2]);
        acc[2][3] = fmaf(xv.z, wv.w, acc[2][3]);
        acc[3][0] = fmaf(xv.w, wv.x, acc[3][0]);
        acc[3][1] = fmaf(xv.w, wv.y, acc[3][1]);
        acc[3][2] = fmaf(xv.w, wv.z, acc[3][2]);
        acc[3][3] = fmaf(xv.w, wv.w, acc[3][3]);
    }
    int p0 = tile*64 + q*4;
    float* o = g_as + (((size_t)b*NN + p0) << 6) + kg*4;
    #pragma unroll
    for (int pi = 0; pi < 4; ++pi) {
        float4 r;
        r.x = fmaxf(acc[pi][0] + bias.x, 0.f);
        r.y = fmaxf(acc[pi][1] + bias.y, 0.f);
        r.z = fmaxf(acc[pi][2] + bias.z, 0.f);
        r.w = fmaxf(acc[pi][3] + bias.w, 0.f);
        *(float4*)(o + (pi << 6)) = r;
    }

    // pair dots from the LDS tile: thread t = pair (t, t+1); full 64-pos sum,
    // no cross-lane reduce.  Staggered quad index spreads banks.
    float ps = 0.f;
    if (t < CC-1) {
        #pragma unroll
        for (int i = 0; i < 16; ++i) {
            int quad = (t + i) & 15;
            float4 a = *(const float4*)(&x_lds[t][quad*4]);
            float4 bq = *(const float4*)(&x_lds[t+1][quad*4]);
            ps = fmaf(a.x, bq.x, ps);
            ps = fmaf(a.y, bq.y, ps);
            ps = fmaf(a.z, bq.z, ps);
            ps = fmaf(a.w, bq.w, ps);
        }
    }
    g_part[(b*32 + tile)*256 + t] = ps;
}

// ---------------- K3: spatial softmax weights (blocks < WBLK) + channel softmax (rest) ----
#define WBLK (BB*NN/32)   // 1024: each block does 32 positions x 8 neighbors
__global__ __launch_bounds__(256) void k_wc() {
    __shared__ float lds_s[256];
    int blk = blockIdx.x;
    int t = threadIdx.x;
    if (blk < WBLK) {
        int pos_local = t >> 3, j = t & 7;
        int idx = blk*32 + pos_local;
        int b = idx >> 11, p = idx & (NN-1);
        int gr = p >> 5, col = p & 31;
        const int dy[8] = {-1,-1,-1, 0,0, 1,1,1};
        const int dx[8] = {-1, 0, 1,-1,1,-1,0,1};
        int qr = gr + dy[j], qc = col + dx[j];
        bool ok = (qr >= 0) && (qr < HH) && (qc >= 0) && (qc < WW);
        int q = ok ? (qr*WW + qc) : p;
        const float4* ap = (const float4*)(g_as + (((size_t)b*NN + p) << 6));
        const float4* sp = (const float4*)(g_as + (((size_t)b*NN + q) << 6) + 32);
        float d = 0.f;
        #pragma unroll
        for (int k4 = 0; k4 < 8; ++k4) {
            float4 a = ap[k4], s = sp[k4];
            d = fmaf(a.x, s.x, d); d = fmaf(a.y, s.y, d);
            d = fmaf(a.z, s.z, d); d = fmaf(a.w, s.w, d);
        }
        float logit = ok ? d : NEGC;
        float m = logit;                       // max over the 8-lane neighbor group
        m = fmaxf(m, __shfl_xor(m, 1, 64));
        m = fmaxf(m, __shfl_xor(m, 2, 64));
        m = fmaxf(m, __shfl_xor(m, 4, 64));
        float e = expf(logit - m);
        float s8 = e;
        s8 += __shfl_xor(s8, 1, 64);
        s8 += __shfl_xor(s8, 2, 64);
        s8 += __shfl_xor(s8, 4, 64);
        g_w8[(size_t)idx*8 + j] = e / s8;
    } else {
        int b = blk - WBLK;
        float s = 0.f;
        #pragma unroll 8
        for (int tile = 0; tile < 32; ++tile) s += g_part[(b*32 + tile)*256 + t];
        lds_s[t] = s;                          // pair-dot for pair (t, t+1)
        __syncthreads();
        int c = t;
        float glo = (c > 0)      ? lds_s[c-1] : NEGC;
        float ghi = (c < CC - 1) ? lds_s[c]   : NEGC;
        float m = fmaxf(glo, ghi);
        float elo = expf(glo - m), ehi = expf(ghi - m);
        float inv = 1.0f / (elo + ehi);
        g_wlo[b*CC + c] = elo * inv;
        g_whi[b*CC + c] = ehi * inv;
    }
}

// ---------------- K4: stencil + channel blend + elu + mix (LDS-staged halo tile) ----
// grid: 2048 blocks = b(16) x strip(8 rows)(8) x cgroup(16 ch)(16); 4 waves = 4 ch each
__global__ __launch_bounds__(256) void k_main(const float* __restrict__ x,
                                              const float* __restrict__ gama_p,
                                              float* __restrict__ out) {
    __shared__ float wtab[256][9];
    __shared__ float xt[18*10*36];
    int blk = blockIdx.x;
    int b = blk >> 7;
    int strip = (blk >> 4) & 7;
    int cg = blk & 15;
    int t = threadIdx.x;
    int r0 = strip << 3;
    int c0 = cg << 4;
    const float* xb = x + (size_t)b*CC*NN;

    {   // stage softmax weights (one thread per position)
        const float4* wsrc = (const float4*)(g_w8 + ((size_t)(b*NN + r0*WW + t))*8);
        float4 w0 = wsrc[0], w1 = wsrc[1];
        wtab[t][0]=w0.x; wtab[t][1]=w0.y; wtab[t][2]=w0.z; wtab[t][3]=w0.w;
        wtab[t][4]=w1.x; wtab[t][5]=w1.y; wtab[t][6]=w1.z; wtab[t][7]=w1.w;
    }
    // stage x halo tile: 18*10 = 180 row-segments x 8 quads = 1440 float4
    for (int i = t; i < 1440; i += 256) {
        int seg = i >> 3, quad = i & 7;
        int ch_s = seg / 10, r_s = seg - ch_s*10;
        int gc = c0 - 1 + ch_s;  gc = (gc < 0) ? 0 : (gc > CC-1 ? CC-1 : gc);
        int gr = r0 - 1 + r_s;   gr = (gr < 0) ? 0 : (gr > HH-1 ? HH-1 : gr);
        float4 v = *(const float4*)(xb + (size_t)gc*NN + gr*WW + quad*4);
        *(float4*)(&xt[(ch_s*10 + r_s)*36 + quad*4]) = v;
    }
    __syncthreads();

    int wave = __builtin_amdgcn_readfirstlane(t >> 6);
    int lane = t & 63;
    int lrow = lane >> 3;            // row within strip
    int lcq  = (lane & 7) << 2;      // column quad start
    float wq[4][8];
    #pragma unroll
    for (int i = 0; i < 4; ++i) {
        int prow = lrow*32 + lcq + i;
        #pragma unroll
        for (int j = 0; j < 8; ++j) wq[i][j] = wtab[prow][j];
    }
    float gama = gama_p[0];
    int cw0 = wave*4;                // this wave's first channel (slot cw0+1)
    int pbase = r0*WW + lane*4;      // for the global store
    float* ob = out + (size_t)b*CC*NN;

    float pm1[4], o0[4];
    {
        float4 v = *(const float4*)(&xt[((cw0+0)*10 + (lrow+1))*36 + lcq]);   // slot c0-1+cw0
        pm1[0]=v.x; pm1[1]=v.y; pm1[2]=v.z; pm1[3]=v.w;
        float4 w = *(const float4*)(&xt[((cw0+1)*10 + (lrow+1))*36 + lcq]);   // own channel
        o0[0]=w.x; o0[1]=w.y; o0[2]=w.z; o0[3]=w.w;
    }
    #pragma unroll
    for (int cc = 0; cc < 4; ++cc) {
        int c = c0 + cw0 + cc;
        int slot = cw0 + 1 + cc;
        float4 v1 = *(const float4*)(&xt[((slot+1)*10 + (lrow+1))*36 + lcq]); // c+1 (clamped)
        float p1[4] = {v1.x, v1.y, v1.z, v1.w};
        float4 va4 = *(const float4*)(&xt[(slot*10 + lrow    )*36 + lcq]);    // row above (clamped)
        float aw[4] = {va4.x, va4.y, va4.z, va4.w};
        float4 vb4 = *(const float4*)(&xt[(slot*10 + lrow + 2)*36 + lcq]);    // row below (clamped)
        float bw[4] = {vb4.x, vb4.y, vb4.z, vb4.w};
        float al  = __shfl_up(aw[3], 1);
        float ar  = __shfl_down(aw[0], 1);
        float ol  = __shfl_up(o0[3], 1);
        float orr = __shfl_down(o0[0], 1);
        float bl  = __shfl_up(bw[3], 1);
        float br  = __shfl_down(bw[0], 1);
        float wlo_c = g_wlo[b*CC + c];
        float whi_c = g_whi[b*CC + c];
        float res[4];
        #pragma unroll
        for (int i = 0; i < 4; ++i) {
            float ul = (i == 0) ? al  : aw[i-1];
            float uu = aw[i];
            float ur = (i == 3) ? ar  : aw[i+1];
            float ll = (i == 0) ? ol  : o0[i-1];
            float rr = (i == 3) ? orr : o0[i+1];
            float dl = (i == 0) ? bl  : bw[i-1];
            float dd = bw[i];
            float dr = (i == 3) ? br  : bw[i+1];
            float hs = wq[i][0]*ul + wq[i][1]*uu + wq[i][2]*ur
                     + wq[i][3]*ll + wq[i][4]*rr
                     + wq[i][5]*dl + wq[i][6]*dd + wq[i][7]*dr;
            float hp = wlo_c*pm1[i] + whi_c*p1[i];
            float h  = hs + hp;
            float el = (h > 0.f) ? h : expm1f(h);
            res[i] = o0[i] + gama*(el - o0[i]);       // (1-g)x + g*h'
        }
        *(float4*)(ob + (size_t)c*NN + pbase) = make_float4(res[0], res[1], res[2], res[3]);
        #pragma unroll
        for (int i = 0; i < 4; ++i) { pm1[i] = o0[i]; o0[i] = p1[i]; }
    }
}

extern "C" void kernel_launch(void* const* d_in, const int* in_sizes, int n_in,
                              void* d_out, int out_size, void* d_ws, size_t ws_size,
                              hipStream_t stream) {
    const float* x    = (const float*)d_in[0];
    const float* wa   = (const float*)d_in[1];
    const float* ga   = (const float*)d_in[2];
    const float* ba   = (const float*)d_in[3];
    const float* ma   = (const float*)d_in[4];
    const float* va   = (const float*)d_in[5];
    const float* wsig = (const float*)d_in[6];
    const float* gs   = (const float*)d_in[7];
    const float* bs   = (const float*)d_in[8];
    const float* ms   = (const float*)d_in[9];
    const float* vs   = (const float*)d_in[10];
    const float* gama = (const float*)d_in[11];
    float* out = (float*)d_out;

    hipLaunchKernelGGL(k_prep, dim3(1),        dim3(256), 0, stream,
                       wa, ga, ba, ma, va, wsig, gs, bs, ms, vs);
    hipLaunchKernelGGL(k_gemm, dim3(512),      dim3(256), 0, stream, x);
    hipLaunchKernelGGL(k_wc,   dim3(WBLK+BB),  dim3(256), 0, stream);
    hipLaunchKernelGGL(k_main, dim3(2048),     dim3(256), 0, stream, x, gama, out);
}

// Round 6
// 57.571 us; speedup vs baseline: 2.0992x; 1.3984x over previous
//
#include <hip/hip_runtime.h>
#include <math.h>

#define BB 16
#define CC 256
#define HH 64
#define WW 32
#define NN (HH*WW)            // 2048
#define NEGC (-9e15f)

// scratch as module-scope device globals (capture-safe); every buffer is fully
// rewritten each call before any read -> deterministic across replays.
__device__ float g_g[BB*CC];              // adjacent-channel dots, g[b][c] = <x[b,c], x[b,c+1]>
__device__ float g_wlo[BB*CC];            // channel-softmax weight on c-1
__device__ float g_whi[BB*CC];            // channel-softmax weight on c+1
__device__ float g_Wt[CC*64];             // BN-folded transposed weights: Wt[c][k], k<32 alpha, k>=32 sigma
__device__ float g_bias[64];              // BN-folded bias
__device__ float g_as[(size_t)BB*NN*64];  // as[b][p][k]: alpha (0..31), sigma (32..63)
__device__ float g_w8[(size_t)BB*NN*8];   // spatial softmax weights per position

// ---------------- K1: prep (16 blocks) + adjacent-channel pair dots (512 blocks) ----
__global__ __launch_bounds__(256) void k_prep_g(const float* __restrict__ x,
        const float* __restrict__ wa, const float* __restrict__ ga,
        const float* __restrict__ ba, const float* __restrict__ ma,
        const float* __restrict__ va, const float* __restrict__ wsig,
        const float* __restrict__ gs, const float* __restrict__ bs,
        const float* __restrict__ ms, const float* __restrict__ vs) {
    int blk = blockIdx.x;
    int t = threadIdx.x;
    if (blk < 16) {                        // prep: BN-folded Wt/bias, c-parallel
        int c = blk*16 + (t >> 4);
        int kq = (t & 15) * 4;
        #pragma unroll
        for (int j = 0; j < 4; ++j) {
            int k = kq + j;
            float inv, w;
            if (k < 32) { inv = ga[k] * rsqrtf(va[k] + 1e-5f); w = wa[k*CC + c]; }
            else { int kk = k - 32; inv = gs[kk] * rsqrtf(vs[kk] + 1e-5f); w = wsig[kk*CC + c]; }
            g_Wt[c*64 + k] = w * inv;
        }
        if (blk == 0 && t < 64) {
            float inv, bb, mm;
            if (t < 32) { inv = ga[t] * rsqrtf(va[t] + 1e-5f); bb = ba[t]; mm = ma[t]; }
            else { int kk = t - 32; inv = gs[kk] * rsqrtf(vs[kk] + 1e-5f); bb = bs[kk]; mm = ms[kk]; }
            g_bias[t] = bb - mm * inv;
        }
        return;
    }
    // pair-dot blocks: 512 = b(16) x pairgroup(32); pairs c=8g..8g+7
    __shared__ float red[8][4];
    int blk2 = blk - 16;
    int b = blk2 >> 5;
    int g8 = blk2 & 31;
    int c0 = g8 << 3;
    int lane = t & 63;
    int wave = t >> 6;
    const float* xb = x + ((size_t)b*CC + c0)*NN;
    float pp[8];
    #pragma unroll
    for (int r = 0; r < 8; ++r) pp[r] = 0.f;
    bool has9 = (c0 + 8) < CC;
    #pragma unroll
    for (int half = 0; half < 2; ++half) {
        int p = t*4 + half*1024;
        float4 v[9];
        #pragma unroll
        for (int r = 0; r < 9; ++r)
            v[r] = (r < 8 || has9) ? *(const float4*)(xb + (size_t)r*NN + p)
                                   : make_float4(0.f,0.f,0.f,0.f);
        #pragma unroll
        for (int r = 0; r < 8; ++r) {
            pp[r] = fmaf(v[r].x, v[r+1].x, pp[r]);
            pp[r] = fmaf(v[r].y, v[r+1].y, pp[r]);
            pp[r] = fmaf(v[r].z, v[r+1].z, pp[r]);
            pp[r] = fmaf(v[r].w, v[r+1].w, pp[r]);
        }
    }
    #pragma unroll
    for (int r = 0; r < 8; ++r) {
        #pragma unroll
        for (int off = 1; off < 64; off <<= 1) pp[r] += __shfl_xor(pp[r], off, 64);
    }
    if (lane == 0) {
        #pragma unroll
        for (int r = 0; r < 8; ++r) red[r][wave] = pp[r];
    }
    __syncthreads();
    if (t < 8) {
        int c = c0 + t;
        if (c < CC - 1)
            g_g[b*CC + c] = red[t][0] + red[t][1] + red[t][2] + red[t][3];
    }
}

// ---------------- K2: alpha/sigma GEMM, c-tiled double-buffered LDS pipeline ----------------
// as[b][p][k] = relu(bias[k] + sum_c Wt[c][k] * x[b][c][p])
// grid: 512 = b(16) x ptile(32, 64 positions).  Per 64-ch tile: x-tile 16KB + W-tile
// 16KB, double-buffered (64KB LDS -> 2 blocks/CU).  Next tile's global loads are
// issued BEFORE the FMA block (async-stage split), ds_write after.
__global__ __launch_bounds__(256) void k_gemm(const float* __restrict__ x) {
    __shared__ float x_lds[2][64*64];   // [buf][c*64 + pos]
    __shared__ float w_lds[2][64*64];   // [buf][c*64 + k]
    int blk = blockIdx.x;
    int b = blk >> 5;
    int tile = blk & 31;
    int t = threadIdx.x;
    const float* xb = x + (size_t)b*CC*NN + tile*64;

    // stage tile 0 into buf 0
    #pragma unroll
    for (int i = 0; i < 4; ++i) {
        int idx = t + i*256;             // quad index (1024 quads = 64c x 16q)
        int c = idx >> 4, quad = idx & 15;
        float4 v = *(const float4*)(xb + (size_t)c*NN + quad*4);
        *(float4*)(&x_lds[0][c*64 + quad*4]) = v;
        float4 w = *(const float4*)(g_Wt + idx*4);
        *(float4*)(&w_lds[0][idx*4]) = w;
    }
    __syncthreads();

    int kg = t & 15;
    int q  = t >> 4;
    float acc[4][4];
    #pragma unroll
    for (int i = 0; i < 4; ++i)
        #pragma unroll
        for (int j = 0; j < 4; ++j) acc[i][j] = 0.f;

    #pragma unroll
    for (int ct = 0; ct < 4; ++ct) {
        int cur = ct & 1;
        float4 sx[4], sw[4];
        if (ct < 3) {                    // issue next tile's global loads early
            #pragma unroll
            for (int i = 0; i < 4; ++i) {
                int idx = t + i*256;
                int c = idx >> 4, quad = idx & 15;
                sx[i] = *(const float4*)(xb + (size_t)((ct+1)*64 + c)*NN + quad*4);
                sw[i] = *(const float4*)(g_Wt + (ct+1)*64*64 + idx*4);
            }
        }
        const float* xt = &x_lds[cur][0];
        const float* wt = &w_lds[cur][0];
        #pragma unroll 8
        for (int c = 0; c < 64; ++c) {
            float4 xv = *(const float4*)(xt + c*64 + q*4);
            float4 wv = *(const float4*)(wt + c*64 + kg*4);
            acc[0][0] = fmaf(xv.x, wv.x, acc[0][0]);
            acc[0][1] = fmaf(xv.x, wv.y, acc[0][1]);
            acc[0][2] = fmaf(xv.x, wv.z, acc[0][2]);
            acc[0][3] = fmaf(xv.x, wv.w, acc[0][3]);
            acc[1][0] = fmaf(xv.y, wv.x, acc[1][0]);
            acc[1][1] = fmaf(xv.y, wv.y, acc[1][1]);
            acc[1][2] = fmaf(xv.y, wv.z, acc[1][2]);
            acc[1][3] = fmaf(xv.y, wv.w, acc[1][3]);
            acc[2][0] = fmaf(xv.z, wv.x, acc[2][0]);
            acc[2][1] = fmaf(xv.z, wv.y, acc[2][1]);
            acc[2][2] = fmaf(xv.z, wv.z, acc[2][2]);
            acc[2][3] = fmaf(xv.z, wv.w, acc[2][3]);
            acc[3][0] = fmaf(xv.w, wv.x, acc[3][0]);
            acc[3][1] = fmaf(xv.w, wv.y, acc[3][1]);
            acc[3][2] = fmaf(xv.w, wv.z, acc[3][2]);
            acc[3][3] = fmaf(xv.w, wv.w, acc[3][3]);
        }
        if (ct < 3) {                    // write staged regs to the other buffer
            int nxt = cur ^ 1;
            #pragma unroll
            for (int i = 0; i < 4; ++i) {
                int idx = t + i*256;
                int c = idx >> 4, quad = idx & 15;
                *(float4*)(&x_lds[nxt][c*64 + quad*4]) = sx[i];
                *(float4*)(&w_lds[nxt][idx*4]) = sw[i];
            }
            __syncthreads();
        }
    }

    float4 bias = *(const float4*)(g_bias + kg*4);
    int p0 = tile*64 + q*4;
    float* o = g_as + (((size_t)b*NN + p0) << 6) + kg*4;
    #pragma unroll
    for (int pi = 0; pi < 4; ++pi) {
        float4 r;
        r.x = fmaxf(acc[pi][0] + bias.x, 0.f);
        r.y = fmaxf(acc[pi][1] + bias.y, 0.f);
        r.z = fmaxf(acc[pi][2] + bias.z, 0.f);
        r.w = fmaxf(acc[pi][3] + bias.w, 0.f);
        *(float4*)(o + (pi << 6)) = r;
    }
}

// ---------------- K3: spatial softmax weights (blocks < WBLK) + channel softmax (rest) ----
#define WBLK (BB*NN/32)   // 1024: each block does 32 positions x 8 neighbors
__global__ __launch_bounds__(256) void k_wc() {
    int blk = blockIdx.x;
    int t = threadIdx.x;
    if (blk < WBLK) {
        int pos_local = t >> 3, j = t & 7;
        int idx = blk*32 + pos_local;
        int b = idx >> 11, p = idx & (NN-1);
        int gr = p >> 5, col = p & 31;
        const int dy[8] = {-1,-1,-1, 0,0, 1,1,1};
        const int dx[8] = {-1, 0, 1,-1,1,-1,0,1};
        int qr = gr + dy[j], qc = col + dx[j];
        bool ok = (qr >= 0) && (qr < HH) && (qc >= 0) && (qc < WW);
        int q = ok ? (qr*WW + qc) : p;
        const float4* ap = (const float4*)(g_as + (((size_t)b*NN + p) << 6));
        const float4* sp = (const float4*)(g_as + (((size_t)b*NN + q) << 6) + 32);
        float d = 0.f;
        #pragma unroll
        for (int k4 = 0; k4 < 8; ++k4) {
            float4 a = ap[k4], s = sp[k4];
            d = fmaf(a.x, s.x, d); d = fmaf(a.y, s.y, d);
            d = fmaf(a.z, s.z, d); d = fmaf(a.w, s.w, d);
        }
        float logit = ok ? d : NEGC;
        float m = logit;                       // max over the 8-lane neighbor group
        m = fmaxf(m, __shfl_xor(m, 1, 64));
        m = fmaxf(m, __shfl_xor(m, 2, 64));
        m = fmaxf(m, __shfl_xor(m, 4, 64));
        float e = expf(logit - m);
        float s8 = e;
        s8 += __shfl_xor(s8, 1, 64);
        s8 += __shfl_xor(s8, 2, 64);
        s8 += __shfl_xor(s8, 4, 64);
        g_w8[(size_t)idx*8 + j] = e / s8;
    } else {
        int b = blk - WBLK;
        int c = t;
        float glo = (c > 0)      ? g_g[b*CC + c - 1] : NEGC;
        float ghi = (c < CC - 1) ? g_g[b*CC + c]     : NEGC;
        float m = fmaxf(glo, ghi);
        float elo = expf(glo - m), ehi = expf(ghi - m);
        float inv = 1.0f / (elo + ehi);
        g_wlo[b*CC + c] = elo * inv;
        g_whi[b*CC + c] = ehi * inv;
    }
}

// ---------------- K4: stencil + channel blend + elu + mix (LDS-staged halo tile) ----
// grid: 2048 blocks = b(16) x strip(8 rows)(8) x cgroup(16 ch)(16); 4 waves = 4 ch each
__global__ __launch_bounds__(256) void k_main(const float* __restrict__ x,
                                              const float* __restrict__ gama_p,
                                              float* __restrict__ out) {
    __shared__ float wtab[256][9];
    __shared__ float xt[18*10*36];
    int blk = blockIdx.x;
    int b = blk >> 7;
    int strip = (blk >> 4) & 7;
    int cg = blk & 15;
    int t = threadIdx.x;
    int r0 = strip << 3;
    int c0 = cg << 4;
    const float* xb = x + (size_t)b*CC*NN;

    {   // stage softmax weights (one thread per position)
        const float4* wsrc = (const float4*)(g_w8 + ((size_t)(b*NN + r0*WW + t))*8);
        float4 w0 = wsrc[0], w1 = wsrc[1];
        wtab[t][0]=w0.x; wtab[t][1]=w0.y; wtab[t][2]=w0.z; wtab[t][3]=w0.w;
        wtab[t][4]=w1.x; wtab[t][5]=w1.y; wtab[t][6]=w1.z; wtab[t][7]=w1.w;
    }
    // stage x halo tile: 18*10 = 180 row-segments x 8 quads = 1440 float4
    for (int i = t; i < 1440; i += 256) {
        int seg = i >> 3, quad = i & 7;
        int ch_s = seg / 10, r_s = seg - ch_s*10;
        int gc = c0 - 1 + ch_s;  gc = (gc < 0) ? 0 : (gc > CC-1 ? CC-1 : gc);
        int gr = r0 - 1 + r_s;   gr = (gr < 0) ? 0 : (gr > HH-1 ? HH-1 : gr);
        float4 v = *(const float4*)(xb + (size_t)gc*NN + gr*WW + quad*4);
        *(float4*)(&xt[(ch_s*10 + r_s)*36 + quad*4]) = v;
    }
    __syncthreads();

    int wave = __builtin_amdgcn_readfirstlane(t >> 6);
    int lane = t & 63;
    int lrow = lane >> 3;            // row within strip
    int lcq  = (lane & 7) << 2;      // column quad start
    float wq[4][8];
    #pragma unroll
    for (int i = 0; i < 4; ++i) {
        int prow = lrow*32 + lcq + i;
        #pragma unroll
        for (int j = 0; j < 8; ++j) wq[i][j] = wtab[prow][j];
    }
    float gama = gama_p[0];
    int cw0 = wave*4;                // this wave's first channel (slot cw0+1)
    int pbase = r0*WW + lane*4;      // for the global store
    float* ob = out + (size_t)b*CC*NN;

    float pm1[4], o0[4];
    {
        float4 v = *(const float4*)(&xt[((cw0+0)*10 + (lrow+1))*36 + lcq]);   // slot c0-1+cw0
        pm1[0]=v.x; pm1[1]=v.y; pm1[2]=v.z; pm1[3]=v.w;
        float4 w = *(const float4*)(&xt[((cw0+1)*10 + (lrow+1))*36 + lcq]);   // own channel
        o0[0]=w.x; o0[1]=w.y; o0[2]=w.z; o0[3]=w.w;
    }
    #pragma unroll
    for (int cc = 0; cc < 4; ++cc) {
        int c = c0 + cw0 + cc;
        int slot = cw0 + 1 + cc;
        float4 v1 = *(const float4*)(&xt[((slot+1)*10 + (lrow+1))*36 + lcq]); // c+1 (clamped)
        float p1[4] = {v1.x, v1.y, v1.z, v1.w};
        float4 va4 = *(const float4*)(&xt[(slot*10 + lrow    )*36 + lcq]);    // row above (clamped)
        float aw[4] = {va4.x, va4.y, va4.z, va4.w};
        float4 vb4 = *(const float4*)(&xt[(slot*10 + lrow + 2)*36 + lcq]);    // row below (clamped)
        float bw[4] = {vb4.x, vb4.y, vb4.z, vb4.w};
        float al  = __shfl_up(aw[3], 1);
        float ar  = __shfl_down(aw[0], 1);
        float ol  = __shfl_up(o0[3], 1);
        float orr = __shfl_down(o0[0], 1);
        float bl  = __shfl_up(bw[3], 1);
        float br  = __shfl_down(bw[0], 1);
        float wlo_c = g_wlo[b*CC + c];
        float whi_c = g_whi[b*CC + c];
        float res[4];
        #pragma unroll
        for (int i = 0; i < 4; ++i) {
            float ul = (i == 0) ? al  : aw[i-1];
            float uu = aw[i];
            float ur = (i == 3) ? ar  : aw[i+1];
            float ll = (i == 0) ? ol  : o0[i-1];
            float rr = (i == 3) ? orr : o0[i+1];
            float dl = (i == 0) ? bl  : bw[i-1];
            float dd = bw[i];
            float dr = (i == 3) ? br  : bw[i+1];
            float hs = wq[i][0]*ul + wq[i][1]*uu + wq[i][2]*ur
                     + wq[i][3]*ll + wq[i][4]*rr
                     + wq[i][5]*dl + wq[i][6]*dd + wq[i][7]*dr;
            float hp = wlo_c*pm1[i] + whi_c*p1[i];
            float h  = hs + hp;
            float el = (h > 0.f) ? h : expm1f(h);
            res[i] = o0[i] + gama*(el - o0[i]);       // (1-g)x + g*h'
        }
        *(float4*)(ob + (size_t)c*NN + pbase) = make_float4(res[0], res[1], res[2], res[3]);
        #pragma unroll
        for (int i = 0; i < 4; ++i) { pm1[i] = o0[i]; o0[i] = p1[i]; }
    }
}

extern "C" void kernel_launch(void* const* d_in, const int* in_sizes, int n_in,
                              void* d_out, int out_size, void* d_ws, size_t ws_size,
                              hipStream_t stream) {
    const float* x    = (const float*)d_in[0];
    const float* wa   = (const float*)d_in[1];
    const float* ga   = (const float*)d_in[2];
    const float* ba   = (const float*)d_in[3];
    const float* ma   = (const float*)d_in[4];
    const float* va   = (const float*)d_in[5];
    const float* wsig = (const float*)d_in[6];
    const float* gs   = (const float*)d_in[7];
    const float* bs   = (const float*)d_in[8];
    const float* ms   = (const float*)d_in[9];
    const float* vs   = (const float*)d_in[10];
    const float* gama = (const float*)d_in[11];
    float* out = (float*)d_out;

    hipLaunchKernelGGL(k_prep_g, dim3(528),     dim3(256), 0, stream, x,
                       wa, ga, ba, ma, va, wsig, gs, bs, ms, vs);
    hipLaunchKernelGGL(k_gemm,   dim3(512),     dim3(256), 0, stream, x);
    hipLaunchKernelGGL(k_wc,     dim3(WBLK+BB), dim3(256), 0, stream);
    hipLaunchKernelGGL(k_main,   dim3(2048),    dim3(256), 0, stream, x, gama, out);
}

// Round 7
// 57.143 us; speedup vs baseline: 2.1149x; 1.0075x over previous
//
#include <hip/hip_runtime.h>
#include <math.h>

#define BB 16
#define CC 256
#define HH 64
#define WW 32
#define NN (HH*WW)            // 2048
#define NEGC (-9e15f)

// scratch as module-scope device globals (capture-safe); every buffer is fully
// rewritten each call before any read -> deterministic across replays.
__device__ float g_wlo[BB*CC];            // channel-softmax weight on c-1
__device__ float g_whi[BB*CC];            // channel-softmax weight on c+1
__device__ float g_Wt[CC*64];             // BN-folded transposed weights: Wt[c][k], k<32 alpha, k>=32 sigma
__device__ float g_bias[64];              // BN-folded bias
__device__ float g_as[(size_t)BB*NN*64];  // as[b][p][k]: alpha (0..31), sigma (32..63)
__device__ float g_part[BB*32*256];       // per-(b,ptile) pair-dot partials over 64 positions
__device__ float g_w8[(size_t)BB*NN*8];   // spatial softmax weights per position

// ---------------- K1: prep (BN-folded Wt/bias), 16 blocks ----------------
__global__ __launch_bounds__(256) void k_prep(
        const float* __restrict__ wa, const float* __restrict__ ga,
        const float* __restrict__ ba, const float* __restrict__ ma,
        const float* __restrict__ va, const float* __restrict__ wsig,
        const float* __restrict__ gs, const float* __restrict__ bs,
        const float* __restrict__ ms, const float* __restrict__ vs) {
    int blk = blockIdx.x;
    int t = threadIdx.x;
    int c = blk*16 + (t >> 4);
    int kq = (t & 15) * 4;
    #pragma unroll
    for (int j = 0; j < 4; ++j) {
        int k = kq + j;
        float inv, w;
        if (k < 32) { inv = ga[k] * rsqrtf(va[k] + 1e-5f); w = wa[k*CC + c]; }
        else { int kk = k - 32; inv = gs[kk] * rsqrtf(vs[kk] + 1e-5f); w = wsig[kk*CC + c]; }
        g_Wt[c*64 + k] = w * inv;
    }
    if (blk == 0 && t < 64) {
        float inv, bb, mm;
        if (t < 32) { inv = ga[t] * rsqrtf(va[t] + 1e-5f); bb = ba[t]; mm = ma[t]; }
        else { int kk = t - 32; inv = gs[kk] * rsqrtf(vs[kk] + 1e-5f); bb = bs[kk]; mm = ms[kk]; }
        g_bias[t] = bb - mm * inv;
    }
}

// ---------------- K2: alpha/sigma GEMM + pair dots, c-tiled dbuf LDS pipeline ----
// as[b][p][k] = relu(bias[k] + sum_c Wt[c][k] * x[b][c][p])
// g_part[b][ptile][c] = sum over the ptile's 64 positions of x[b,c,p]*x[b,c+1,p]
// grid: 512 = b(16) x ptile(32, 64 positions).  Per 64-ch tile: x 16KB + W 16KB,
// double-buffered; next tile's global loads issued BEFORE the FMA block.
// Pair-dots computed per-tile from the LDS x tile (x read from HBM exactly once).
__global__ __launch_bounds__(256) void k_gemm(const float* __restrict__ x) {
    __shared__ float x_lds[2][64*64];   // [buf][c*64 + pos]
    __shared__ float w_lds[2][64*64];   // [buf][c*64 + k]
    int blk = blockIdx.x;
    int b = blk >> 5;
    int tile = blk & 31;
    int t = threadIdx.x;
    const float* xb = x + (size_t)b*CC*NN + tile*64;

    // stage tile 0 into buf 0
    #pragma unroll
    for (int i = 0; i < 4; ++i) {
        int idx = t + i*256;             // quad index (1024 quads = 64c x 16q)
        int c = idx >> 4, quad = idx & 15;
        float4 v = *(const float4*)(xb + (size_t)c*NN + quad*4);
        *(float4*)(&x_lds[0][c*64 + quad*4]) = v;
        float4 w = *(const float4*)(g_Wt + idx*4);
        *(float4*)(&w_lds[0][idx*4]) = w;
    }
    __syncthreads();

    int kg = t & 15;
    int q  = t >> 4;
    float acc[4][4];
    #pragma unroll
    for (int i = 0; i < 4; ++i)
        #pragma unroll
        for (int j = 0; j < 4; ++j) acc[i][j] = 0.f;

    #pragma unroll
    for (int ct = 0; ct < 4; ++ct) {
        int cur = ct & 1;
        float4 sx[4], sw[4];
        if (ct < 3) {                    // issue next tile's global loads early
            #pragma unroll
            for (int i = 0; i < 4; ++i) {
                int idx = t + i*256;
                int c = idx >> 4, quad = idx & 15;
                sx[i] = *(const float4*)(xb + (size_t)((ct+1)*64 + c)*NN + quad*4);
                sw[i] = *(const float4*)(g_Wt + (ct+1)*64*64 + idx*4);
            }
        }
        const float* xt = &x_lds[cur][0];
        const float* wt = &w_lds[cur][0];
        #pragma unroll 8
        for (int c = 0; c < 64; ++c) {
            float4 xv = *(const float4*)(xt + c*64 + q*4);
            float4 wv = *(const float4*)(wt + c*64 + kg*4);
            acc[0][0] = fmaf(xv.x, wv.x, acc[0][0]);
            acc[0][1] = fmaf(xv.x, wv.y, acc[0][1]);
            acc[0][2] = fmaf(xv.x, wv.z, acc[0][2]);
            acc[0][3] = fmaf(xv.x, wv.w, acc[0][3]);
            acc[1][0] = fmaf(xv.y, wv.x, acc[1][0]);
            acc[1][1] = fmaf(xv.y, wv.y, acc[1][1]);
            acc[1][2] = fmaf(xv.y, wv.z, acc[1][2]);
            acc[1][3] = fmaf(xv.y, wv.w, acc[1][3]);
            acc[2][0] = fmaf(xv.z, wv.x, acc[2][0]);
            acc[2][1] = fmaf(xv.z, wv.y, acc[2][1]);
            acc[2][2] = fmaf(xv.z, wv.z, acc[2][2]);
            acc[2][3] = fmaf(xv.z, wv.w, acc[2][3]);
            acc[3][0] = fmaf(xv.w, wv.x, acc[3][0]);
            acc[3][1] = fmaf(xv.w, wv.y, acc[3][1]);
            acc[3][2] = fmaf(xv.w, wv.z, acc[3][2]);
            acc[3][3] = fmaf(xv.w, wv.w, acc[3][3]);
        }

        // pair-dot partials for pairs c = ct*64 + r (reads x_lds[cur]; the
        // staged ds_write below targets the OTHER buffer, so no extra sync).
        {
            int r = t >> 2, qg = t & 3;
            int c = ct*64 + r;
            float pp = 0.f;
            if (c < CC-1) {
                const float* rowA = xt + r*64;
                if (r < 63) {
                    const float* rowB = xt + (r+1)*64;
                    #pragma unroll
                    for (int j = 0; j < 4; ++j) {
                        int quad = ((qg + r) & 3) + 4*j;   // stagger: 8 bank-quads
                        float4 a  = *(const float4*)(rowA + quad*4);
                        float4 bv = *(const float4*)(rowB + quad*4);
                        pp = fmaf(a.x, bv.x, pp); pp = fmaf(a.y, bv.y, pp);
                        pp = fmaf(a.z, bv.z, pp); pp = fmaf(a.w, bv.w, pp);
                    }
                } else {                 // boundary pair: next tile's first row (L2-hot)
                    const float* rowBg = xb + (size_t)(ct*64 + 64)*NN;
                    #pragma unroll
                    for (int j = 0; j < 4; ++j) {
                        int quad = ((qg + r) & 3) + 4*j;
                        float4 a  = *(const float4*)(rowA + quad*4);
                        float4 bv = *(const float4*)(rowBg + quad*4);
                        pp = fmaf(a.x, bv.x, pp); pp = fmaf(a.y, bv.y, pp);
                        pp = fmaf(a.z, bv.z, pp); pp = fmaf(a.w, bv.w, pp);
                    }
                }
            }
            pp += __shfl_xor(pp, 1, 64);
            pp += __shfl_xor(pp, 2, 64);
            if (qg == 0) g_part[(b*32 + tile)*256 + c] = pp;   // c==255 -> 0
        }

        if (ct < 3) {                    // write staged regs to the other buffer
            int nxt = cur ^ 1;
            #pragma unroll
            for (int i = 0; i < 4; ++i) {
                int idx = t + i*256;
                int c = idx >> 4, quad = idx & 15;
                *(float4*)(&x_lds[nxt][c*64 + quad*4]) = sx[i];
                *(float4*)(&w_lds[nxt][idx*4]) = sw[i];
            }
            __syncthreads();
        }
    }

    float4 bias = *(const float4*)(g_bias + kg*4);
    int p0 = tile*64 + q*4;
    float* o = g_as + (((size_t)b*NN + p0) << 6) + kg*4;
    #pragma unroll
    for (int pi = 0; pi < 4; ++pi) {
        float4 r;
        r.x = fmaxf(acc[pi][0] + bias.x, 0.f);
        r.y = fmaxf(acc[pi][1] + bias.y, 0.f);
        r.z = fmaxf(acc[pi][2] + bias.z, 0.f);
        r.w = fmaxf(acc[pi][3] + bias.w, 0.f);
        *(float4*)(o + (pi << 6)) = r;
    }
}

// ---------------- K3: spatial softmax weights (blocks < WBLK) + channel softmax (rest) ----
#define WBLK (BB*NN/32)   // 1024: each block does 32 positions x 8 neighbors
__global__ __launch_bounds__(256) void k_wc() {
    __shared__ float lds_s[256];
    int blk = blockIdx.x;
    int t = threadIdx.x;
    if (blk < WBLK) {
        int pos_local = t >> 3, j = t & 7;
        int idx = blk*32 + pos_local;
        int b = idx >> 11, p = idx & (NN-1);
        int gr = p >> 5, col = p & 31;
        const int dy[8] = {-1,-1,-1, 0,0, 1,1,1};
        const int dx[8] = {-1, 0, 1,-1,1,-1,0,1};
        int qr = gr + dy[j], qc = col + dx[j];
        bool ok = (qr >= 0) && (qr < HH) && (qc >= 0) && (qc < WW);
        int q = ok ? (qr*WW + qc) : p;
        const float4* ap = (const float4*)(g_as + (((size_t)b*NN + p) << 6));
        const float4* sp = (const float4*)(g_as + (((size_t)b*NN + q) << 6) + 32);
        float d = 0.f;
        #pragma unroll
        for (int k4 = 0; k4 < 8; ++k4) {
            float4 a = ap[k4], s = sp[k4];
            d = fmaf(a.x, s.x, d); d = fmaf(a.y, s.y, d);
            d = fmaf(a.z, s.z, d); d = fmaf(a.w, s.w, d);
        }
        float logit = ok ? d : NEGC;
        float m = logit;                       // max over the 8-lane neighbor group
        m = fmaxf(m, __shfl_xor(m, 1, 64));
        m = fmaxf(m, __shfl_xor(m, 2, 64));
        m = fmaxf(m, __shfl_xor(m, 4, 64));
        float e = expf(logit - m);
        float s8 = e;
        s8 += __shfl_xor(s8, 1, 64);
        s8 += __shfl_xor(s8, 2, 64);
        s8 += __shfl_xor(s8, 4, 64);
        g_w8[(size_t)idx*8 + j] = e / s8;
    } else {
        int b = blk - WBLK;
        float s = 0.f;
        #pragma unroll 8
        for (int tile = 0; tile < 32; ++tile) s += g_part[(b*32 + tile)*256 + t];
        lds_s[t] = s;                          // pair-dot for pair (t, t+1)
        __syncthreads();
        int c = t;
        float glo = (c > 0)      ? lds_s[c-1] : NEGC;
        float ghi = (c < CC - 1) ? lds_s[c]   : NEGC;
        float m = fmaxf(glo, ghi);
        float elo = expf(glo - m), ehi = expf(ghi - m);
        float inv = 1.0f / (elo + ehi);
        g_wlo[b*CC + c] = elo * inv;
        g_whi[b*CC + c] = ehi * inv;
    }
}

// ---------------- K4: stencil + channel blend + elu + mix (LDS-staged halo tile) ----
// grid: 2048 blocks = b(16) x strip(8 rows)(8) x cgroup(16 ch)(16); 4 waves = 4 ch each
__global__ __launch_bounds__(256) void k_main(const float* __restrict__ x,
                                              const float* __restrict__ gama_p,
                                              float* __restrict__ out) {
    __shared__ float wtab[256][9];
    __shared__ float xt[18*10*36];
    int blk = blockIdx.x;
    int b = blk >> 7;
    int strip = (blk >> 4) & 7;
    int cg = blk & 15;
    int t = threadIdx.x;
    int r0 = strip << 3;
    int c0 = cg << 4;
    const float* xb = x + (size_t)b*CC*NN;

    {   // stage softmax weights (one thread per position)
        const float4* wsrc = (const float4*)(g_w8 + ((size_t)(b*NN + r0*WW + t))*8);
        float4 w0 = wsrc[0], w1 = wsrc[1];
        wtab[t][0]=w0.x; wtab[t][1]=w0.y; wtab[t][2]=w0.z; wtab[t][3]=w0.w;
        wtab[t][4]=w1.x; wtab[t][5]=w1.y; wtab[t][6]=w1.z; wtab[t][7]=w1.w;
    }
    // stage x halo tile: 18*10 = 180 row-segments x 8 quads = 1440 float4
    for (int i = t; i < 1440; i += 256) {
        int seg = i >> 3, quad = i & 7;
        int ch_s = seg / 10, r_s = seg - ch_s*10;
        int gc = c0 - 1 + ch_s;  gc = (gc < 0) ? 0 : (gc > CC-1 ? CC-1 : gc);
        int gr = r0 - 1 + r_s;   gr = (gr < 0) ? 0 : (gr > HH-1 ? HH-1 : gr);
        float4 v = *(const float4*)(xb + (size_t)gc*NN + gr*WW + quad*4);
        *(float4*)(&xt[(ch_s*10 + r_s)*36 + quad*4]) = v;
    }
    __syncthreads();

    int wave = __builtin_amdgcn_readfirstlane(t >> 6);
    int lane = t & 63;
    int lrow = lane >> 3;            // row within strip
    int lcq  = (lane & 7) << 2;      // column quad start
    float wq[4][8];
    #pragma unroll
    for (int i = 0; i < 4; ++i) {
        int prow = lrow*32 + lcq + i;
        #pragma unroll
        for (int j = 0; j < 8; ++j) wq[i][j] = wtab[prow][j];
    }
    float gama = gama_p[0];
    int cw0 = wave*4;                // this wave's first channel (slot cw0+1)
    int pbase = r0*WW + lane*4;      // for the global store
    float* ob = out + (size_t)b*CC*NN;

    float pm1[4], o0[4];
    {
        float4 v = *(const float4*)(&xt[((cw0+0)*10 + (lrow+1))*36 + lcq]);   // slot c0-1+cw0
        pm1[0]=v.x; pm1[1]=v.y; pm1[2]=v.z; pm1[3]=v.w;
        float4 w = *(const float4*)(&xt[((cw0+1)*10 + (lrow+1))*36 + lcq]);   // own channel
        o0[0]=w.x; o0[1]=w.y; o0[2]=w.z; o0[3]=w.w;
    }
    #pragma unroll
    for (int cc = 0; cc < 4; ++cc) {
        int c = c0 + cw0 + cc;
        int slot = cw0 + 1 + cc;
        float4 v1 = *(const float4*)(&xt[((slot+1)*10 + (lrow+1))*36 + lcq]); // c+1 (clamped)
        float p1[4] = {v1.x, v1.y, v1.z, v1.w};
        float4 va4 = *(const float4*)(&xt[(slot*10 + lrow    )*36 + lcq]);    // row above (clamped)
        float aw[4] = {va4.x, va4.y, va4.z, va4.w};
        float4 vb4 = *(const float4*)(&xt[(slot*10 + lrow + 2)*36 + lcq]);    // row below (clamped)
        float bw[4] = {vb4.x, vb4.y, vb4.z, vb4.w};
        float al  = __shfl_up(aw[3], 1);
        float ar  = __shfl_down(aw[0], 1);
        float ol  = __shfl_up(o0[3], 1);
        float orr = __shfl_down(o0[0], 1);
        float bl  = __shfl_up(bw[3], 1);
        float br  = __shfl_down(bw[0], 1);
        float wlo_c = g_wlo[b*CC + c];
        float whi_c = g_whi[b*CC + c];
        float res[4];
        #pragma unroll
        for (int i = 0; i < 4; ++i) {
            float ul = (i == 0) ? al  : aw[i-1];
            float uu = aw[i];
            float ur = (i == 3) ? ar  : aw[i+1];
            float ll = (i == 0) ? ol  : o0[i-1];
            float rr = (i == 3) ? orr : o0[i+1];
            float dl = (i == 0) ? bl  : bw[i-1];
            float dd = bw[i];
            float dr = (i == 3) ? br  : bw[i+1];
            float hs = wq[i][0]*ul + wq[i][1]*uu + wq[i][2]*ur
                     + wq[i][3]*ll + wq[i][4]*rr
                     + wq[i][5]*dl + wq[i][6]*dd + wq[i][7]*dr;
            float hp = wlo_c*pm1[i] + whi_c*p1[i];
            float h  = hs + hp;
            float el = (h > 0.f) ? h : expm1f(h);
            res[i] = o0[i] + gama*(el - o0[i]);       // (1-g)x + g*h'
        }
        *(float4*)(ob + (size_t)c*NN + pbase) = make_float4(res[0], res[1], res[2], res[3]);
        #pragma unroll
        for (int i = 0; i < 4; ++i) { pm1[i] = o0[i]; o0[i] = p1[i]; }
    }
}

extern "C" void kernel_launch(void* const* d_in, const int* in_sizes, int n_in,
                              void* d_out, int out_size, void* d_ws, size_t ws_size,
                              hipStream_t stream) {
    const float* x    = (const float*)d_in[0];
    const float* wa   = (const float*)d_in[1];
    const float* ga   = (const float*)d_in[2];
    const float* ba   = (const float*)d_in[3];
    const float* ma   = (const float*)d_in[4];
    const float* va   = (const float*)d_in[5];
    const float* wsig = (const float*)d_in[6];
    const float* gs   = (const float*)d_in[7];
    const float* bs   = (const float*)d_in[8];
    const float* ms   = (const float*)d_in[9];
    const float* vs   = (const float*)d_in[10];
    const float* gama = (const float*)d_in[11];
    float* out = (float*)d_out;

    hipLaunchKernelGGL(k_prep, dim3(16),       dim3(256), 0, stream,
                       wa, ga, ba, ma, va, wsig, gs, bs, ms, vs);
    hipLaunchKernelGGL(k_gemm, dim3(512),      dim3(256), 0, stream, x);
    hipLaunchKernelGGL(k_wc,   dim3(WBLK+BB),  dim3(256), 0, stream);
    hipLaunchKernelGGL(k_main, dim3(2048),     dim3(256), 0, stream, x, gama, out);
}